// Round 8
// baseline (625.821 us; speedup 1.0000x reference)
//
#include <hip/hip_runtime.h>
#include <math.h>

#define D_MODELC 256
#define N_LAYERSC 6
#define N_HEADSC 8
#define D_FFC 1024
#define HEAD_DIMC 32
#define B_SZ 4
#define T_SEQ 2048
#define M_ROWS 8192
#define QKV_N 768
#define KSPLIT 4

typedef short bf16x8 __attribute__((ext_vector_type(8)));
typedef short bf16x4 __attribute__((ext_vector_type(4)));
typedef float f32x4  __attribute__((ext_vector_type(4)));
typedef unsigned u32x4 __attribute__((ext_vector_type(4)));
typedef unsigned short u16;

// scale(1/sqrt(32)) * log2(e) folded into wq at conversion time
#define QSCALE 0.25503488f

// LDS XOR swizzle for 128B-row-stride tiles (kept from R5/R6; see rule #21:
// linear gload dest + pre-swizzled global source + swizzled read).
#define SWZ(b) ((b) ^ (((b) >> 3) & 0x70))

// direct global->LDS DMA, 16 bytes per lane (literal size required)
__device__ __forceinline__ void gload16(const void* g, void* l) {
    __builtin_amdgcn_global_load_lds(
        (const __attribute__((address_space(1))) void*)g,
        (__attribute__((address_space(3))) void*)l, 16, 0, 0);
}

__device__ __forceinline__ u16 f2bf(float x) {
    unsigned u = __builtin_bit_cast(unsigned, x);
    u += 0x7FFF + ((u >> 16) & 1);          // round-to-nearest-even
    return (u16)(u >> 16);
}

__device__ __forceinline__ float bf2f(short x) {
    return __builtin_bit_cast(float, (unsigned)((u16)x) << 16);
}

// packed bf16 pair (truncating) via single v_perm_b32: low16=a.hi, high16=b.hi
__device__ __forceinline__ unsigned pack2bf(float a, float b) {
    return __builtin_amdgcn_perm(__builtin_bit_cast(unsigned, b),
                                 __builtin_bit_cast(unsigned, a), 0x07060302u);
}

// A&S 7.1.26 erf (|err|<=1.5e-7), one v_exp + one v_rcp; exact-gelu drop-in.
__device__ __forceinline__ float fast_gelu(float x) {
    float y  = x * 0.70710678118654752f;
    float ay = __builtin_fabsf(y);
    float t  = __builtin_amdgcn_rcpf(1.0f + 0.3275911f * ay);
    float p  = t * (0.254829592f + t * (-0.284496736f + t * (1.421413741f
               + t * (-1.453152027f + t * 1.061405429f))));
    float e  = __builtin_amdgcn_exp2f(-ay * ay * 1.4426950408889634f);
    float er = 1.0f - p * e;
    er = y < 0.0f ? -er : er;
    return 0.5f * x * (1.0f + er);
}

// ---------------------------------------------------------------------------
// prep_all: ALL weight prep + ln_copy in ONE dispatch (unchanged).
// ---------------------------------------------------------------------------
__device__ __forceinline__ void transpose_tile(
    const float* __restrict__ src, u16* __restrict__ dst,
    int K, int N, int k0, int n0, float scale, float (*ts)[33])
{
    const int r = threadIdx.x >> 3, c4 = (threadIdx.x & 7) * 4;
    const float4 v = *(const float4*)(src + (size_t)(k0 + r) * N + n0 + c4);
    ts[r][c4 + 0] = v.x; ts[r][c4 + 1] = v.y;
    ts[r][c4 + 2] = v.z; ts[r][c4 + 3] = v.w;
    __syncthreads();
    bf16x4 o;
#pragma unroll
    for (int i = 0; i < 4; i++) o[i] = (short)f2bf(ts[c4 + i][r] * scale);
    *(bf16x4*)(dst + (size_t)(n0 + r) * K + k0 + c4) = o;
}

__global__ __launch_bounds__(256) void prep_all(
    const float* __restrict__ wq, const float* __restrict__ wk,
    const float* __restrict__ wv, const float* __restrict__ wo,
    const float* __restrict__ w1, const float* __restrict__ w2,
    const float* __restrict__ bq, const float* __restrict__ bk,
    const float* __restrict__ bv,
    u16* __restrict__ wqkv_t, u16* __restrict__ wo_t,
    u16* __restrict__ w1_t, u16* __restrict__ w2_t,
    float* __restrict__ qkvb,
    const float* __restrict__ x, const float* __restrict__ gamma,
    const float* __restrict__ beta, float* __restrict__ X,
    u16* __restrict__ Y)
{
    __shared__ float ts[32][33];
    const int bid = blockIdx.x;
    if (bid < 1152) {                 // wq/wk/wv: 3 x 6 x 64 tiles
        const int sec = bid / 384, t = bid % 384;
        const int z = t >> 6, rem = t & 63, ty = rem >> 3, tx = rem & 7;
        const float* src = sec == 0 ? wq : (sec == 1 ? wk : wv);
        transpose_tile(src + (size_t)z * 65536,
                       wqkv_t + (size_t)z * QKV_N * 256 + sec * 256 * 256,
                       256, 256, ty * 32, tx * 32,
                       sec == 0 ? QSCALE : 1.0f, ts);
    } else if (bid < 1536) {          // wo
        const int t = bid - 1152;
        const int z = t >> 6, rem = t & 63, ty = rem >> 3, tx = rem & 7;
        transpose_tile(wo + (size_t)z * 65536, wo_t + (size_t)z * 65536,
                       256, 256, ty * 32, tx * 32, 1.0f, ts);
    } else if (bid < 3072) {          // w1: K=256, N=1024, 6 x 256 tiles
        const int t = bid - 1536;
        const int z = t >> 8, rem = t & 255, ty = rem >> 5, tx = rem & 31;
        transpose_tile(w1 + (size_t)z * 262144, w1_t + (size_t)z * 262144,
                       256, D_FFC, ty * 32, tx * 32, 1.0f, ts);
    } else if (bid < 4608) {          // w2: K=1024, N=256
        const int t = bid - 3072;
        const int z = t >> 8, rem = t & 255, ty = rem >> 3, tx = rem & 7;
        transpose_tile(w2 + (size_t)z * 262144, w2_t + (size_t)z * 262144,
                       D_FFC, 256, ty * 32, tx * 32, 1.0f, ts);
    } else if (bid < 4626) {          // fused qkv bias
        const int i = (bid - 4608) * 256 + threadIdx.x;
        const int l = i / QKV_N, j = i % QKV_N;
        float v;
        if (j < 256)      v = bq[l * 256 + j] * QSCALE;
        else if (j < 512) v = bk[l * 256 + j - 256];
        else              v = bv[l * 256 + j - 512];
        qkvb[i] = v;
    } else {                          // X = x; Y = bf16(LN1_0(x))
        const int w = threadIdx.x >> 6, lane = threadIdx.x & 63;
        const int row = (bid - 4626) * 4 + w;
        const float4 v = *(const float4*)(x + (size_t)row * 256 + lane * 4);
        *(float4*)(X + (size_t)row * 256 + lane * 4) = v;
        float sum = v.x + v.y + v.z + v.w;
        float sq  = v.x * v.x + v.y * v.y + v.z * v.z + v.w * v.w;
#pragma unroll
        for (int off = 32; off > 0; off >>= 1) {
            sum += __shfl_xor(sum, off, 64);
            sq  += __shfl_xor(sq,  off, 64);
        }
        float mu  = sum * (1.0f / 256.0f);
        float var = sq * (1.0f / 256.0f) - mu * mu;
        float rr  = rsqrtf(var + 1e-5f);
        const float4 g  = *(const float4*)(gamma + lane * 4);
        const float4 bb = *(const float4*)(beta + lane * 4);
        bf16x4 o;
        o[0] = (short)f2bf((v.x - mu) * rr * g.x + bb.x);
        o[1] = (short)f2bf((v.y - mu) * rr * g.y + bb.y);
        o[2] = (short)f2bf((v.z - mu) * rr * g.z + bb.z);
        o[3] = (short)f2bf((v.w - mu) * rr * g.w + bb.w);
        *(bf16x4*)(Y + (size_t)row * 256 + lane * 4) = o;
    }
}

// ---------------------------------------------------------------------------
// MFMA GEMM, 128x128 tile, BK=64, global_load_lds staging (unchanged R6).
// ---------------------------------------------------------------------------
template <int EPI>
__global__ __launch_bounds__(256) void mfma_gemm(
    const u16* __restrict__ A, const u16* __restrict__ Bt,
    const float* __restrict__ bias, u16* __restrict__ Vout,
    void* __restrict__ Cout, int N, int K)
{
    __shared__ u16 As[128 * 64];
    __shared__ u16 Bs[128 * 64];
    const int tid = threadIdx.x, w = tid >> 6, lane = tid & 63;
    const int c = lane & 15, quad = lane >> 4;
    const int row0 = blockIdx.y * 128, col0 = blockIdx.x * 128;
    const int wr = w >> 1, wc = w & 1;
    const int cswz = (c & 7) << 4;

    int flv[4], rA[4], colA[4];
#pragma unroll
    for (int ci = 0; ci < 4; ci++) {
        flv[ci]  = (w * 4 + ci) * 1024 + lane * 16;
        const int fsw = SWZ(flv[ci]);
        rA[ci]   = fsw >> 7;
        colA[ci] = (fsw & 127) >> 1;
    }

    f32x4 acc[4][4] = {};

    for (int k0 = 0; k0 < K; k0 += 64) {
        __syncthreads();
#pragma unroll
        for (int ci = 0; ci < 4; ci++) {
            gload16(A  + (size_t)(row0 + rA[ci]) * K + k0 + colA[ci],
                    (char*)As + flv[ci]);
            gload16(Bt + (size_t)(col0 + rA[ci]) * K + k0 + colA[ci],
                    (char*)Bs + flv[ci]);
        }
        __syncthreads();
#pragma unroll
        for (int kk = 0; kk < 2; kk++) {
            bf16x8 af[4], bfv[4];
#pragma unroll
            for (int i = 0; i < 4; i++)
                af[i] = *(const bf16x8*)((const char*)As +
                    ((((wr * 64 + i * 16 + c) * 64 + kk * 32 + quad * 8) * 2) ^ cswz));
#pragma unroll
            for (int j = 0; j < 4; j++)
                bfv[j] = *(const bf16x8*)((const char*)Bs +
                    ((((wc * 64 + j * 16 + c) * 64 + kk * 32 + quad * 8) * 2) ^ cswz));
#pragma unroll
            for (int i = 0; i < 4; i++)
#pragma unroll
                for (int j = 0; j < 4; j++)
                    acc[i][j] = __builtin_amdgcn_mfma_f32_16x16x32_bf16(
                        af[i], bfv[j], acc[i][j], 0, 0, 0);
        }
    }

    float bj[4];
#pragma unroll
    for (int j = 0; j < 4; j++) bj[j] = bias[col0 + wc * 64 + j * 16 + c];

    if (EPI == 3 && col0 >= 512) {
#pragma unroll
        for (int i = 0; i < 4; i++) {
            const int tok = row0 + wr * 64 + i * 16 + quad * 4;
#pragma unroll
            for (int j = 0; j < 4; j++) {
                const int dim = col0 - 512 + wc * 64 + j * 16 + c;
                bf16x4 o;
#pragma unroll
                for (int r = 0; r < 4; r++) o[r] = (short)f2bf(acc[i][j][r] + bj[j]);
                *(bf16x4*)&Vout[(size_t)dim * M_ROWS + tok] = o;
            }
        }
        return;
    }

#pragma unroll
    for (int i = 0; i < 4; i++) {
#pragma unroll
        for (int r = 0; r < 4; r++) {
            const int gr = row0 + wr * 64 + i * 16 + quad * 4 + r;
#pragma unroll
            for (int j = 0; j < 4; j++) {
                const int gc = col0 + wc * 64 + j * 16 + c;
                float v = acc[i][j][r] + bj[j];
                if (EPI == 2) v = fast_gelu(v);
                ((u16*)Cout)[(size_t)gr * N + gc] = f2bf(v);
            }
        }
    }
}

// ---------------------------------------------------------------------------
// GEMM (N=256, BM=32, BN=256) + residual + optional fused LayerNorm.
// MERGE=1: A is the CONTIGUOUS 4-part attention partials buffer
// PO[4][M_ROWS][256] with Lmrg[4][M_ROWS][8]; the 4-way key-split merge
// (sum p_i) * rcp(sum l_i) happens inline during A staging.
// ---------------------------------------------------------------------------
template <int DOLN, int MERGE>
__global__ __launch_bounds__(256) void gemm_ln(
    const u16* __restrict__ A, const float* __restrict__ Lmrg,
    const u16* __restrict__ Bt, const float* __restrict__ bias,
    const float* __restrict__ resid, float* __restrict__ Xout,
    const float* __restrict__ gamma, const float* __restrict__ beta,
    u16* __restrict__ Nout, int K)
{
    __shared__ u16 As[32 * 64];
    __shared__ u16 Bs[256 * 64];
    __shared__ float2 red[4][32];
    const int tid = threadIdx.x, w = tid >> 6, lane = tid & 63;
    const int c = lane & 15, quad = lane >> 4;
    const int row0 = blockIdx.x * 32;
    const int cswz = (c & 7) << 4;

    const int flA  = w * 1024 + lane * 16;      // linear LDS slot (bytes)
    const int fsA  = SWZ(flA);
    const int rA_m = flA >> 7, colA_m = (flA & 127) >> 1;   // MERGE reg-path
    const int rA_g = fsA >> 7, colA_g = (fsA & 127) >> 1;   // gload path

    int flB[8], rB[8], colB[8];
#pragma unroll
    for (int ci = 0; ci < 8; ci++) {
        flB[ci]  = (w * 8 + ci) * 1024 + lane * 16;
        const int fsB = SWZ(flB[ci]);
        rB[ci]   = fsB >> 7;
        colB[ci] = (fsB & 127) >> 1;
    }

    f32x4 acc[2][4] = {};

    auto loadA = [&](int gc) -> bf16x8 {
        const int row = row0 + rA_m;
        const int head = gc >> 5;
        float ls = 0.f;
#pragma unroll
        for (int p = 0; p < KSPLIT; p++)
            ls += Lmrg[(size_t)p * M_ROWS * 8 + (size_t)row * 8 + head];
        const float inv = __builtin_amdgcn_rcpf(ls);
        float s[8] = {0.f, 0.f, 0.f, 0.f, 0.f, 0.f, 0.f, 0.f};
#pragma unroll
        for (int p = 0; p < KSPLIT; p++) {
            bf16x8 a = *(const bf16x8*)(A + (size_t)p * M_ROWS * 256
                                          + (size_t)row * 256 + gc);
#pragma unroll
            for (int j = 0; j < 8; j++) s[j] += bf2f(a[j]);
        }
        bf16x8 o;
#pragma unroll
        for (int j = 0; j < 8; j++) o[j] = (short)f2bf(s[j] * inv);
        return o;
    };

    bf16x8 pA;
    if (MERGE) pA = loadA(colA_m);

    for (int k0 = 0; k0 < K; k0 += 64) {
        __syncthreads();
#pragma unroll
        for (int ci = 0; ci < 8; ci++)
            gload16(Bt + (size_t)rB[ci] * K + k0 + colB[ci], (char*)Bs + flB[ci]);
        if (MERGE) {
            *(bf16x8*)((char*)As + fsA) = pA;
        } else {
            gload16(A + (size_t)(row0 + rA_g) * K + k0 + colA_g, (char*)As + flA);
        }
        __syncthreads();
        if (MERGE && k0 + 64 < K)
            pA = loadA(k0 + 64 + colA_m);   // lands during compute
#pragma unroll
        for (int kk = 0; kk < 2; kk++) {
            bf16x8 af[2], bfv[4];
#pragma unroll
            for (int i = 0; i < 2; i++)
                af[i] = *(const bf16x8*)((const char*)As +
                    ((((i * 16 + c) * 64 + kk * 32 + quad * 8) * 2) ^ cswz));
#pragma unroll
            for (int j = 0; j < 4; j++)
                bfv[j] = *(const bf16x8*)((const char*)Bs +
                    ((((w * 64 + j * 16 + c) * 64 + kk * 32 + quad * 8) * 2) ^ cswz));
#pragma unroll
            for (int i = 0; i < 2; i++)
#pragma unroll
                for (int j = 0; j < 4; j++)
                    acc[i][j] = __builtin_amdgcn_mfma_f32_16x16x32_bf16(
                        af[i], bfv[j], acc[i][j], 0, 0, 0);
        }
    }

    float bj[4];
#pragma unroll
    for (int j = 0; j < 4; j++) bj[j] = bias[w * 64 + j * 16 + c];
    float xv[2][4][4];
#pragma unroll
    for (int i = 0; i < 2; i++)
#pragma unroll
        for (int r = 0; r < 4; r++) {
            const int gr = row0 + i * 16 + quad * 4 + r;
#pragma unroll
            for (int j = 0; j < 4; j++) {
                const int gc = w * 64 + j * 16 + c;
                xv[i][j][r] = acc[i][j][r] + bj[j] + resid[(size_t)gr * 256 + gc];
            }
        }

    if (DOLN) {
        float sm[2][4], sp[2][4];
#pragma unroll
        for (int i = 0; i < 2; i++)
#pragma unroll
            for (int r = 0; r < 4; r++) {
                float s = 0.f, q = 0.f;
#pragma unroll
                for (int j = 0; j < 4; j++) { s += xv[i][j][r]; q += xv[i][j][r] * xv[i][j][r]; }
                sm[i][r] = s; sp[i][r] = q;
            }
#pragma unroll
        for (int off = 1; off < 16; off <<= 1)
#pragma unroll
            for (int i = 0; i < 2; i++)
#pragma unroll
                for (int r = 0; r < 4; r++) {
                    sm[i][r] += __shfl_xor(sm[i][r], off, 64);
                    sp[i][r] += __shfl_xor(sp[i][r], off, 64);
                }
        __syncthreads();
        if (c == 0) {
#pragma unroll
            for (int i = 0; i < 2; i++)
#pragma unroll
                for (int r = 0; r < 4; r++)
                    red[w][i * 16 + quad * 4 + r] = make_float2(sm[i][r], sp[i][r]);
        }
        __syncthreads();
#pragma unroll
        for (int i = 0; i < 2; i++)
#pragma unroll
            for (int r = 0; r < 4; r++) {
                const int row = i * 16 + quad * 4 + r;
                float2 t0 = red[0][row], t1 = red[1][row];
                float2 t2 = red[2][row], t3 = red[3][row];
                float S = (t0.x + t1.x) + (t2.x + t3.x);
                float Q = (t0.y + t1.y) + (t2.y + t3.y);
                float mu = S * (1.0f / 256.0f);
                float var = Q * (1.0f / 256.0f) - mu * mu;
                float rr = rsqrtf(var + 1e-5f);
                const int gr = row0 + row;
#pragma unroll
                for (int j = 0; j < 4; j++) {
                    const int gc = w * 64 + j * 16 + c;
                    float x = xv[i][j][r];
                    Xout[(size_t)gr * 256 + gc] = x;
                    Nout[(size_t)gr * 256 + gc] =
                        f2bf((x - mu) * rr * gamma[gc] + beta[gc]);
                }
            }
    } else {
#pragma unroll
        for (int i = 0; i < 2; i++)
#pragma unroll
            for (int r = 0; r < 4; r++) {
                const int gr = row0 + i * 16 + quad * 4 + r;
#pragma unroll
                for (int j = 0; j < 4; j++)
                    Xout[(size_t)gr * 256 + w * 64 + j * 16 + c] = xv[i][j][r];
            }
    }
}

// ---------------------------------------------------------------------------
// MFMA flash attention, key-split x4 (was x2): part = blockIdx.x & 3 owns
// keys [part*512, part*512+512) -> 4 supertile iterations per block instead
// of 8. Halves the serial barrier/exp critical path; doubles block-level
// parallelism (2048 blocks). Partials to PO[part], l to Lp[part].
// ---------------------------------------------------------------------------
__global__ __launch_bounds__(256) void attn_kernel(
    const u16* __restrict__ QKV, const u16* __restrict__ VT,
    u16* __restrict__ PO, float* __restrict__ Lp)
{
    const int h = blockIdx.y, b = blockIdx.z;
    const int part = blockIdx.x & (KSPLIT - 1);
    const int q0 = (blockIdx.x >> 2) * 128;
    const int tid = threadIdx.x, w = tid >> 6, lane = tid & 63;
    const int c = lane & 15, quad = lane >> 4;

    __shared__ u16 Kf[4096];
    __shared__ u16 Vf[4096];

    const u16* qp = QKV + (size_t)(b * T_SEQ + q0 + w * 32 + c) * QKV_N + h * 32 + quad * 8;
    bf16x8 aQ0 = *(const bf16x8*)qp;
    bf16x8 aQ1 = *(const bf16x8*)(qp + 16 * QKV_N);

    const bf16x8 bOnes = {0x3F80, 0x3F80, 0x3F80, 0x3F80,
                          0x3F80, 0x3F80, 0x3F80, 0x3F80};

    f32x4 O[2][2] = {};
    f32x4 Ol0 = {0.f, 0.f, 0.f, 0.f}, Ol1 = {0.f, 0.f, 0.f, 0.f};

    const u16* kgp = QKV + (size_t)(b * T_SEQ + w * 16 + c) * QKV_N + 256 + h * 32 + quad * 8;
    const u16* vgp = VT + ((size_t)h * 32 + (lane & 31)) * M_ROWS + b * T_SEQ
                     + (w * 2 + (lane >> 5)) * 8;
    u16* kfw = Kf + w * 512 + lane * 8;

    const int vd  = lane & 31, vdh = vd >> 4, vc = vd & 15, vhi = lane >> 5;
    const int vkh = w >> 1, vseg = w & 1;
    const int voff = ((((vkh * 2 + vdh) * 4 + 2 * vhi) * 16 + vc) * 8) + vseg * 4;

    const int kbeg = part * (T_SEQ / KSPLIT);
    const int kend = kbeg + T_SEQ / KSPLIT;

    bf16x8 gK0 = *(const bf16x8*)(kgp + (size_t)kbeg * QKV_N);
    bf16x8 gK1 = *(const bf16x8*)(kgp + (size_t)(kbeg + 64) * QKV_N);
    bf16x8 gV0 = *(const bf16x8*)(vgp + kbeg);
    bf16x8 gV1 = *(const bf16x8*)(vgp + kbeg + 64);

    for (int k0 = kbeg; k0 < kend; k0 += 128) {
        __syncthreads();
        *(bf16x8*)kfw          = gK0;
        *(bf16x8*)(kfw + 2048) = gK1;
        {
            bf16x4 l0v = __builtin_shufflevector(gV0, gV0, 0, 1, 2, 3);
            bf16x4 h0v = __builtin_shufflevector(gV0, gV0, 4, 5, 6, 7);
            bf16x4 l1v = __builtin_shufflevector(gV1, gV1, 0, 1, 2, 3);
            bf16x4 h1v = __builtin_shufflevector(gV1, gV1, 4, 5, 6, 7);
            *(bf16x4*)&Vf[voff]              = l0v;
            *(bf16x4*)&Vf[voff + 128]        = h0v;
            *(bf16x4*)&Vf[2048 + voff]       = l1v;
            *(bf16x4*)&Vf[2048 + voff + 128] = h1v;
        }
        __syncthreads();
        if (k0 + 128 < kend) {
            gK0 = *(const bf16x8*)(kgp + (size_t)(k0 + 128) * QKV_N);
            gK1 = *(const bf16x8*)(kgp + (size_t)(k0 + 192) * QKV_N);
            gV0 = *(const bf16x8*)(vgp + k0 + 128);
            gV1 = *(const bf16x8*)(vgp + k0 + 192);
        }

#pragma unroll
        for (int hf = 0; hf < 2; hf++) {
            const u16* Kb = Kf + hf * 2048;
            const u16* Vb = Vf + hf * 2048;

            unsigned pk0[4][2], pk1[4][2];
#pragma unroll
            for (int g = 0; g < 4; g++) {
                bf16x8 aK = *(const bf16x8*)&Kb[g * 512 + lane * 8];
                f32x4 S0 = __builtin_amdgcn_mfma_f32_16x16x32_bf16(
                    aK, aQ0, (f32x4){0.f, 0.f, 0.f, 0.f}, 0, 0, 0);
                f32x4 S1 = __builtin_amdgcn_mfma_f32_16x16x32_bf16(
                    aK, aQ1, (f32x4){0.f, 0.f, 0.f, 0.f}, 0, 0, 0);
                pk0[g][0] = pack2bf(__builtin_amdgcn_exp2f(S0[0]),
                                    __builtin_amdgcn_exp2f(S0[1]));
                pk0[g][1] = pack2bf(__builtin_amdgcn_exp2f(S0[2]),
                                    __builtin_amdgcn_exp2f(S0[3]));
                pk1[g][0] = pack2bf(__builtin_amdgcn_exp2f(S1[0]),
                                    __builtin_amdgcn_exp2f(S1[1]));
                pk1[g][1] = pack2bf(__builtin_amdgcn_exp2f(S1[2]),
                                    __builtin_amdgcn_exp2f(S1[3]));
            }

            __builtin_amdgcn_s_setprio(1);
#pragma unroll
            for (int kh = 0; kh < 2; kh++) {
                bf16x8 aP0 = __builtin_bit_cast(bf16x8,
                    (u32x4){pk0[2 * kh][0], pk0[2 * kh][1],
                            pk0[2 * kh + 1][0], pk0[2 * kh + 1][1]});
                bf16x8 aP1 = __builtin_bit_cast(bf16x8,
                    (u32x4){pk1[2 * kh][0], pk1[2 * kh][1],
                            pk1[2 * kh + 1][0], pk1[2 * kh + 1][1]});
                Ol0 = __builtin_amdgcn_mfma_f32_16x16x32_bf16(aP0, bOnes, Ol0, 0, 0, 0);
                Ol1 = __builtin_amdgcn_mfma_f32_16x16x32_bf16(aP1, bOnes, Ol1, 0, 0, 0);
#pragma unroll
                for (int dh = 0; dh < 2; dh++) {
                    bf16x8 bV = *(const bf16x8*)&Vb[((kh * 2 + dh) * 64 + lane) * 8];
                    O[0][dh] = __builtin_amdgcn_mfma_f32_16x16x32_bf16(aP0, bV, O[0][dh], 0, 0, 0);
                    O[1][dh] = __builtin_amdgcn_mfma_f32_16x16x32_bf16(aP1, bV, O[1][dh], 0, 0, 0);
                }
            }
            __builtin_amdgcn_s_setprio(0);
        }
    }

    u16* pb = PO + (size_t)part * M_ROWS * 256
              + (size_t)(b * T_SEQ + q0 + w * 32) * 256 + h * 32;
    if (c == 0) {
        float* lb = Lp + (size_t)part * M_ROWS * 8
                    + (size_t)(b * T_SEQ + q0 + w * 32) * 8 + h;
#pragma unroll
        for (int r = 0; r < 4; r++) {
            lb[(size_t)(quad * 4 + r) * 8]      = Ol0[r];
            lb[(size_t)(16 + quad * 4 + r) * 8] = Ol1[r];
        }
    }
#pragma unroll
    for (int r = 0; r < 4; r++) {
        int src = quad * 4 + r;
        pb[(size_t)src * 256 + c]             = f2bf(O[0][0][r]);
        pb[(size_t)src * 256 + 16 + c]        = f2bf(O[0][1][r]);
        pb[(size_t)(16 + src) * 256 + c]      = f2bf(O[1][0][r]);
        pb[(size_t)(16 + src) * 256 + 16 + c] = f2bf(O[1][1][r]);
    }
}

// ---------------------------------------------------------------------------
extern "C" void kernel_launch(void* const* d_in, const int* in_sizes, int n_in,
                              void* d_out, int out_size, void* d_ws, size_t ws_size,
                              hipStream_t stream)
{
    const float* x     = (const float*)d_in[0];
    const float* ln1_s = (const float*)d_in[1];
    const float* ln1_b = (const float*)d_in[2];
    const float* wq    = (const float*)d_in[3];
    const float* bq    = (const float*)d_in[4];
    const float* wk    = (const float*)d_in[5];
    const float* bk    = (const float*)d_in[6];
    const float* wv    = (const float*)d_in[7];
    const float* bv    = (const float*)d_in[8];
    const float* wo    = (const float*)d_in[9];
    const float* bo    = (const float*)d_in[10];
    const float* ln2_s = (const float*)d_in[11];
    const float* ln2_b = (const float*)d_in[12];
    const float* w1    = (const float*)d_in[13];
    const float* b1    = (const float*)d_in[14];
    const float* w2    = (const float*)d_in[15];
    const float* b2    = (const float*)d_in[16];

    float* X = (float*)d_out;                   // fp32 residual stream

    u16* normed = (u16*)d_ws;                               // 8192*256
    u16* qkv    = normed + (size_t)M_ROWS * 256;            // 8192*768
    u16* PO4    = qkv + (size_t)M_ROWS * QKV_N;             // 4 x 8192*256
    u16* h1     = qkv;   // spans qkv+PO4[0]: 8192*1024 (PO4[0] consumed by then)
    u16* wqkv_t = PO4 + (size_t)KSPLIT * M_ROWS * 256;      // 6*768*256
    u16* wo_t   = wqkv_t + (size_t)N_LAYERSC * QKV_N * 256; // 6*256*256
    u16* w1_t   = wo_t + (size_t)N_LAYERSC * 256 * 256;     // 6*1024*256
    u16* w2_t   = w1_t + (size_t)N_LAYERSC * D_FFC * 256;   // 6*256*1024
    float* qkvb = (float*)(w2_t + (size_t)N_LAYERSC * 256 * D_FFC); // 6*768 fp32
    u16* VTb    = (u16*)(qkvb + N_LAYERSC * QKV_N);         // 256*8192
    float* Lp   = (float*)(VTb + (size_t)256 * M_ROWS);     // 4*8192*8 fp32

    dim3 blk(256);

    // ---- ALL weight prep + X=x + ln1(layer0) in one dispatch
    prep_all<<<dim3(4626 + M_ROWS / 4), blk, 0, stream>>>(
        wq, wk, wv, wo, w1, w2, bq, bk, bv,
        wqkv_t, wo_t, w1_t, w2_t, qkvb,
        x, ln1_s, ln1_b, X, normed);

    dim3 g_qkv(QKV_N / 128, M_ROWS / 128);              // (6,64)
    dim3 g_ff(D_FFC / 128, M_ROWS / 128);               // (8,64)
    dim3 g_ln32(M_ROWS / 32);                           // 256 blocks
    dim3 g_attn(KSPLIT * T_SEQ / 128, N_HEADSC, B_SZ);  // (64,8,4) = 2048 blocks

    for (int l = 0; l < N_LAYERSC; l++) {
        mfma_gemm<3><<<g_qkv, blk, 0, stream>>>(
            normed, wqkv_t + (size_t)l * QKV_N * 256, qkvb + l * QKV_N,
            VTb, qkv, QKV_N, 256);
        attn_kernel<<<g_attn, blk, 0, stream>>>(qkv, VTb, PO4, Lp);
        // Wo + resid + ln2, with the 4-way key-split merge fused into A-staging
        gemm_ln<1, 1><<<g_ln32, blk, 0, stream>>>(
            PO4, Lp, wo_t + (size_t)l * 256 * 256, bo + l * 256, X,
            X, ln2_s + l * 256, ln2_b + l * 256, VTb, 256);
        mfma_gemm<2><<<g_ff, blk, 0, stream>>>(
            VTb, w1_t + (size_t)l * D_FFC * 256, b1 + l * D_FFC,
            nullptr, h1, D_FFC, 256);
        if (l + 1 < N_LAYERSC) {
            gemm_ln<1, 0><<<g_ln32, blk, 0, stream>>>(
                h1, nullptr, w2_t + (size_t)l * 256 * D_FFC,
                b2 + l * 256, X, X, ln1_s + (l + 1) * 256,
                ln1_b + (l + 1) * 256, normed, D_FFC);
        } else {
            gemm_ln<0, 0><<<g_ln32, blk, 0, stream>>>(
                h1, nullptr, w2_t + (size_t)l * 256 * D_FFC,
                b2 + l * 256, X, X, nullptr, nullptr, nullptr, D_FFC);
        }
    }
}

// Round 9
// 614.753 us; speedup vs baseline: 1.0180x; 1.0180x over previous
//
#include <hip/hip_runtime.h>
#include <math.h>

#define D_MODELC 256
#define N_LAYERSC 6
#define N_HEADSC 8
#define D_FFC 1024
#define HEAD_DIMC 32
#define B_SZ 4
#define T_SEQ 2048
#define M_ROWS 8192
#define QKV_N 768
#define KSPLIT 2

typedef short bf16x8 __attribute__((ext_vector_type(8)));
typedef short bf16x4 __attribute__((ext_vector_type(4)));
typedef float f32x4  __attribute__((ext_vector_type(4)));
typedef unsigned u32x4 __attribute__((ext_vector_type(4)));
typedef unsigned short u16;

// scale(1/sqrt(32)) * log2(e) folded into wq at conversion time
#define QSCALE 0.25503488f

// LDS XOR swizzle for 128B-row-stride tiles (rule #21: linear gload dest +
// pre-swizzled global source + swizzled read).
#define SWZ(b) ((b) ^ (((b) >> 3) & 0x70))

// direct global->LDS DMA, 16 bytes per lane (literal size required)
__device__ __forceinline__ void gload16(const void* g, void* l) {
    __builtin_amdgcn_global_load_lds(
        (const __attribute__((address_space(1))) void*)g,
        (__attribute__((address_space(3))) void*)l, 16, 0, 0);
}

__device__ __forceinline__ u16 f2bf(float x) {
    unsigned u = __builtin_bit_cast(unsigned, x);
    u += 0x7FFF + ((u >> 16) & 1);          // round-to-nearest-even
    return (u16)(u >> 16);
}

__device__ __forceinline__ float bf2f(short x) {
    return __builtin_bit_cast(float, (unsigned)((u16)x) << 16);
}

// packed bf16 pair (truncating) via single v_perm_b32: low16=a.hi, high16=b.hi
__device__ __forceinline__ unsigned pack2bf(float a, float b) {
    return __builtin_amdgcn_perm(__builtin_bit_cast(unsigned, b),
                                 __builtin_bit_cast(unsigned, a), 0x07060302u);
}

// A&S 7.1.26 erf (|err|<=1.5e-7), one v_exp + one v_rcp; exact-gelu drop-in.
__device__ __forceinline__ float fast_gelu(float x) {
    float y  = x * 0.70710678118654752f;
    float ay = __builtin_fabsf(y);
    float t  = __builtin_amdgcn_rcpf(1.0f + 0.3275911f * ay);
    float p  = t * (0.254829592f + t * (-0.284496736f + t * (1.421413741f
               + t * (-1.453152027f + t * 1.061405429f))));
    float e  = __builtin_amdgcn_exp2f(-ay * ay * 1.4426950408889634f);
    float er = 1.0f - p * e;
    er = y < 0.0f ? -er : er;
    return 0.5f * x * (1.0f + er);
}

// ---------------------------------------------------------------------------
// prep_all: ALL weight prep + ln_copy in ONE dispatch (unchanged).
// ---------------------------------------------------------------------------
__device__ __forceinline__ void transpose_tile(
    const float* __restrict__ src, u16* __restrict__ dst,
    int K, int N, int k0, int n0, float scale, float (*ts)[33])
{
    const int r = threadIdx.x >> 3, c4 = (threadIdx.x & 7) * 4;
    const float4 v = *(const float4*)(src + (size_t)(k0 + r) * N + n0 + c4);
    ts[r][c4 + 0] = v.x; ts[r][c4 + 1] = v.y;
    ts[r][c4 + 2] = v.z; ts[r][c4 + 3] = v.w;
    __syncthreads();
    bf16x4 o;
#pragma unroll
    for (int i = 0; i < 4; i++) o[i] = (short)f2bf(ts[c4 + i][r] * scale);
    *(bf16x4*)(dst + (size_t)(n0 + r) * K + k0 + c4) = o;
}

__global__ __launch_bounds__(256) void prep_all(
    const float* __restrict__ wq, const float* __restrict__ wk,
    const float* __restrict__ wv, const float* __restrict__ wo,
    const float* __restrict__ w1, const float* __restrict__ w2,
    const float* __restrict__ bq, const float* __restrict__ bk,
    const float* __restrict__ bv,
    u16* __restrict__ wqkv_t, u16* __restrict__ wo_t,
    u16* __restrict__ w1_t, u16* __restrict__ w2_t,
    float* __restrict__ qkvb,
    const float* __restrict__ x, const float* __restrict__ gamma,
    const float* __restrict__ beta, float* __restrict__ X,
    u16* __restrict__ Y)
{
    __shared__ float ts[32][33];
    const int bid = blockIdx.x;
    if (bid < 1152) {                 // wq/wk/wv: 3 x 6 x 64 tiles
        const int sec = bid / 384, t = bid % 384;
        const int z = t >> 6, rem = t & 63, ty = rem >> 3, tx = rem & 7;
        const float* src = sec == 0 ? wq : (sec == 1 ? wk : wv);
        transpose_tile(src + (size_t)z * 65536,
                       wqkv_t + (size_t)z * QKV_N * 256 + sec * 256 * 256,
                       256, 256, ty * 32, tx * 32,
                       sec == 0 ? QSCALE : 1.0f, ts);
    } else if (bid < 1536) {          // wo
        const int t = bid - 1152;
        const int z = t >> 6, rem = t & 63, ty = rem >> 3, tx = rem & 7;
        transpose_tile(wo + (size_t)z * 65536, wo_t + (size_t)z * 65536,
                       256, 256, ty * 32, tx * 32, 1.0f, ts);
    } else if (bid < 3072) {          // w1: K=256, N=1024, 6 x 256 tiles
        const int t = bid - 1536;
        const int z = t >> 8, rem = t & 255, ty = rem >> 5, tx = rem & 31;
        transpose_tile(w1 + (size_t)z * 262144, w1_t + (size_t)z * 262144,
                       256, D_FFC, ty * 32, tx * 32, 1.0f, ts);
    } else if (bid < 4608) {          // w2: K=1024, N=256
        const int t = bid - 3072;
        const int z = t >> 8, rem = t & 255, ty = rem >> 3, tx = rem & 7;
        transpose_tile(w2 + (size_t)z * 262144, w2_t + (size_t)z * 262144,
                       D_FFC, 256, ty * 32, tx * 32, 1.0f, ts);
    } else if (bid < 4626) {          // fused qkv bias
        const int i = (bid - 4608) * 256 + threadIdx.x;
        const int l = i / QKV_N, j = i % QKV_N;
        float v;
        if (j < 256)      v = bq[l * 256 + j] * QSCALE;
        else if (j < 512) v = bk[l * 256 + j - 256];
        else              v = bv[l * 256 + j - 512];
        qkvb[i] = v;
    } else {                          // X = x; Y = bf16(LN1_0(x))
        const int w = threadIdx.x >> 6, lane = threadIdx.x & 63;
        const int row = (bid - 4626) * 4 + w;
        const float4 v = *(const float4*)(x + (size_t)row * 256 + lane * 4);
        *(float4*)(X + (size_t)row * 256 + lane * 4) = v;
        float sum = v.x + v.y + v.z + v.w;
        float sq  = v.x * v.x + v.y * v.y + v.z * v.z + v.w * v.w;
#pragma unroll
        for (int off = 32; off > 0; off >>= 1) {
            sum += __shfl_xor(sum, off, 64);
            sq  += __shfl_xor(sq,  off, 64);
        }
        float mu  = sum * (1.0f / 256.0f);
        float var = sq * (1.0f / 256.0f) - mu * mu;
        float rr  = rsqrtf(var + 1e-5f);
        const float4 g  = *(const float4*)(gamma + lane * 4);
        const float4 bb = *(const float4*)(beta + lane * 4);
        bf16x4 o;
        o[0] = (short)f2bf((v.x - mu) * rr * g.x + bb.x);
        o[1] = (short)f2bf((v.y - mu) * rr * g.y + bb.y);
        o[2] = (short)f2bf((v.z - mu) * rr * g.z + bb.z);
        o[3] = (short)f2bf((v.w - mu) * rr * g.w + bb.w);
        *(bf16x4*)(Y + (size_t)row * 256 + lane * 4) = o;
    }
}

// ---------------------------------------------------------------------------
// MFMA GEMM, 128x128 tile, BK=64, global_load_lds staging (unchanged).
// ---------------------------------------------------------------------------
template <int EPI>
__global__ __launch_bounds__(256) void mfma_gemm(
    const u16* __restrict__ A, const u16* __restrict__ Bt,
    const float* __restrict__ bias, u16* __restrict__ Vout,
    void* __restrict__ Cout, int N, int K)
{
    __shared__ u16 As[128 * 64];
    __shared__ u16 Bs[128 * 64];
    const int tid = threadIdx.x, w = tid >> 6, lane = tid & 63;
    const int c = lane & 15, quad = lane >> 4;
    const int row0 = blockIdx.y * 128, col0 = blockIdx.x * 128;
    const int wr = w >> 1, wc = w & 1;
    const int cswz = (c & 7) << 4;

    int flv[4], rA[4], colA[4];
#pragma unroll
    for (int ci = 0; ci < 4; ci++) {
        flv[ci]  = (w * 4 + ci) * 1024 + lane * 16;
        const int fsw = SWZ(flv[ci]);
        rA[ci]   = fsw >> 7;
        colA[ci] = (fsw & 127) >> 1;
    }

    f32x4 acc[4][4] = {};

    for (int k0 = 0; k0 < K; k0 += 64) {
        __syncthreads();
#pragma unroll
        for (int ci = 0; ci < 4; ci++) {
            gload16(A  + (size_t)(row0 + rA[ci]) * K + k0 + colA[ci],
                    (char*)As + flv[ci]);
            gload16(Bt + (size_t)(col0 + rA[ci]) * K + k0 + colA[ci],
                    (char*)Bs + flv[ci]);
        }
        __syncthreads();
#pragma unroll
        for (int kk = 0; kk < 2; kk++) {
            bf16x8 af[4], bfv[4];
#pragma unroll
            for (int i = 0; i < 4; i++)
                af[i] = *(const bf16x8*)((const char*)As +
                    ((((wr * 64 + i * 16 + c) * 64 + kk * 32 + quad * 8) * 2) ^ cswz));
#pragma unroll
            for (int j = 0; j < 4; j++)
                bfv[j] = *(const bf16x8*)((const char*)Bs +
                    ((((wc * 64 + j * 16 + c) * 64 + kk * 32 + quad * 8) * 2) ^ cswz));
#pragma unroll
            for (int i = 0; i < 4; i++)
#pragma unroll
                for (int j = 0; j < 4; j++)
                    acc[i][j] = __builtin_amdgcn_mfma_f32_16x16x32_bf16(
                        af[i], bfv[j], acc[i][j], 0, 0, 0);
        }
    }

    float bj[4];
#pragma unroll
    for (int j = 0; j < 4; j++) bj[j] = bias[col0 + wc * 64 + j * 16 + c];

    if (EPI == 3 && col0 >= 512) {
#pragma unroll
        for (int i = 0; i < 4; i++) {
            const int tok = row0 + wr * 64 + i * 16 + quad * 4;
#pragma unroll
            for (int j = 0; j < 4; j++) {
                const int dim = col0 - 512 + wc * 64 + j * 16 + c;
                bf16x4 o;
#pragma unroll
                for (int r = 0; r < 4; r++) o[r] = (short)f2bf(acc[i][j][r] + bj[j]);
                *(bf16x4*)&Vout[(size_t)dim * M_ROWS + tok] = o;
            }
        }
        return;
    }

#pragma unroll
    for (int i = 0; i < 4; i++) {
#pragma unroll
        for (int r = 0; r < 4; r++) {
            const int gr = row0 + wr * 64 + i * 16 + quad * 4 + r;
#pragma unroll
            for (int j = 0; j < 4; j++) {
                const int gc = col0 + wc * 64 + j * 16 + c;
                float v = acc[i][j][r] + bj[j];
                if (EPI == 2) v = fast_gelu(v);
                ((u16*)Cout)[(size_t)gr * N + gc] = f2bf(v);
            }
        }
    }
}

// ---------------------------------------------------------------------------
// GEMM (N=256, BM=32, BN=256) + residual + optional fused LayerNorm.
// NOW 512 THREADS / 8 WARPS: each warp owns a 32-col slice -> 8 waves/CU
// (was 4) on these 1-block/CU dispatches — doubles latency-hiding TLP.
// A-staging handled by waves 0-3 (wave-uniform). MERGE=1: 2-way key-split
// partials merged inline during A staging.
// ---------------------------------------------------------------------------
template <int DOLN, int MERGE>
__global__ __launch_bounds__(512) void gemm_ln(
    const u16* __restrict__ A, const float* __restrict__ Lmrg,
    const u16* __restrict__ Bt, const float* __restrict__ bias,
    const float* __restrict__ resid, float* __restrict__ Xout,
    const float* __restrict__ gamma, const float* __restrict__ beta,
    u16* __restrict__ Nout, int K)
{
    __shared__ u16 As[32 * 64];
    __shared__ u16 Bs[256 * 64];
    __shared__ float2 red[8][32];
    const int tid = threadIdx.x, w = tid >> 6, lane = tid & 63;
    const int c = lane & 15, quad = lane >> 4;
    const int row0 = blockIdx.x * 32;
    const int cswz = (c & 7) << 4;

    // A staging: 4 KB staged by tid<256 (waves 0-3), 16B each
    const int flA  = tid * 16;                  // valid for tid<256
    const bool doA = tid < 256;
    const int fsA  = SWZ(flA);
    const int rA_m = flA >> 7, colA_m = (flA & 127) >> 1;   // MERGE reg-path
    const int rA_g = fsA >> 7, colA_g = (fsA & 127) >> 1;   // gload path

    // B staging: 32 KB staged by all 512 threads, 4 x 16B each
    int flB[4], rB[4], colB[4];
#pragma unroll
    for (int ci = 0; ci < 4; ci++) {
        flB[ci]  = (w * 4 + ci) * 1024 + lane * 16;
        const int fsB = SWZ(flB[ci]);
        rB[ci]   = fsB >> 7;
        colB[ci] = (fsB & 127) >> 1;
    }

    f32x4 acc[2][2] = {};

    auto loadA = [&](int gc) -> bf16x8 {
        const int row = row0 + rA_m;
        const int head = gc >> 5;
        float ls = 0.f;
#pragma unroll
        for (int p = 0; p < KSPLIT; p++)
            ls += Lmrg[(size_t)p * M_ROWS * 8 + (size_t)row * 8 + head];
        const float inv = __builtin_amdgcn_rcpf(ls);
        float s[8] = {0.f, 0.f, 0.f, 0.f, 0.f, 0.f, 0.f, 0.f};
#pragma unroll
        for (int p = 0; p < KSPLIT; p++) {
            bf16x8 a = *(const bf16x8*)(A + (size_t)p * M_ROWS * 256
                                          + (size_t)row * 256 + gc);
#pragma unroll
            for (int j = 0; j < 8; j++) s[j] += bf2f(a[j]);
        }
        bf16x8 o;
#pragma unroll
        for (int j = 0; j < 8; j++) o[j] = (short)f2bf(s[j] * inv);
        return o;
    };

    bf16x8 pA;
    if (MERGE && doA) pA = loadA(colA_m);

    for (int k0 = 0; k0 < K; k0 += 64) {
        __syncthreads();
#pragma unroll
        for (int ci = 0; ci < 4; ci++)
            gload16(Bt + (size_t)rB[ci] * K + k0 + colB[ci], (char*)Bs + flB[ci]);
        if (MERGE) {
            if (doA) *(bf16x8*)((char*)As + fsA) = pA;
        } else {
            if (doA) gload16(A + (size_t)(row0 + rA_g) * K + k0 + colA_g,
                             (char*)As + flA);
        }
        __syncthreads();
        if (MERGE && doA && k0 + 64 < K)
            pA = loadA(k0 + 64 + colA_m);   // lands during compute
#pragma unroll
        for (int kk = 0; kk < 2; kk++) {
            bf16x8 af[2], bfv[2];
#pragma unroll
            for (int i = 0; i < 2; i++)
                af[i] = *(const bf16x8*)((const char*)As +
                    ((((i * 16 + c) * 64 + kk * 32 + quad * 8) * 2) ^ cswz));
#pragma unroll
            for (int j = 0; j < 2; j++)
                bfv[j] = *(const bf16x8*)((const char*)Bs +
                    ((((w * 32 + j * 16 + c) * 64 + kk * 32 + quad * 8) * 2) ^ cswz));
#pragma unroll
            for (int i = 0; i < 2; i++)
#pragma unroll
                for (int j = 0; j < 2; j++)
                    acc[i][j] = __builtin_amdgcn_mfma_f32_16x16x32_bf16(
                        af[i], bfv[j], acc[i][j], 0, 0, 0);
        }
    }

    float bj[2];
#pragma unroll
    for (int j = 0; j < 2; j++) bj[j] = bias[w * 32 + j * 16 + c];
    float xv[2][2][4];
#pragma unroll
    for (int i = 0; i < 2; i++)
#pragma unroll
        for (int r = 0; r < 4; r++) {
            const int gr = row0 + i * 16 + quad * 4 + r;
#pragma unroll
            for (int j = 0; j < 2; j++) {
                const int gc = w * 32 + j * 16 + c;
                xv[i][j][r] = acc[i][j][r] + bj[j] + resid[(size_t)gr * 256 + gc];
            }
        }

    if (DOLN) {
        float sm[2][4], sp[2][4];
#pragma unroll
        for (int i = 0; i < 2; i++)
#pragma unroll
            for (int r = 0; r < 4; r++) {
                float s = 0.f, q = 0.f;
#pragma unroll
                for (int j = 0; j < 2; j++) { s += xv[i][j][r]; q += xv[i][j][r] * xv[i][j][r]; }
                sm[i][r] = s; sp[i][r] = q;
            }
#pragma unroll
        for (int off = 1; off < 16; off <<= 1)
#pragma unroll
            for (int i = 0; i < 2; i++)
#pragma unroll
                for (int r = 0; r < 4; r++) {
                    sm[i][r] += __shfl_xor(sm[i][r], off, 64);
                    sp[i][r] += __shfl_xor(sp[i][r], off, 64);
                }
        __syncthreads();
        if (c == 0) {
#pragma unroll
            for (int i = 0; i < 2; i++)
#pragma unroll
                for (int r = 0; r < 4; r++)
                    red[w][i * 16 + quad * 4 + r] = make_float2(sm[i][r], sp[i][r]);
        }
        __syncthreads();
#pragma unroll
        for (int i = 0; i < 2; i++)
#pragma unroll
            for (int r = 0; r < 4; r++) {
                const int row = i * 16 + quad * 4 + r;
                float S = 0.f, Q = 0.f;
#pragma unroll
                for (int wp = 0; wp < 8; wp++) {
                    S += red[wp][row].x;
                    Q += red[wp][row].y;
                }
                float mu = S * (1.0f / 256.0f);
                float var = Q * (1.0f / 256.0f) - mu * mu;
                float rr = rsqrtf(var + 1e-5f);
                const int gr = row0 + row;
#pragma unroll
                for (int j = 0; j < 2; j++) {
                    const int gc = w * 32 + j * 16 + c;
                    float x = xv[i][j][r];
                    Xout[(size_t)gr * 256 + gc] = x;
                    Nout[(size_t)gr * 256 + gc] =
                        f2bf((x - mu) * rr * gamma[gc] + beta[gc]);
                }
            }
    } else {
#pragma unroll
        for (int i = 0; i < 2; i++)
#pragma unroll
            for (int r = 0; r < 4; r++) {
                const int gr = row0 + i * 16 + quad * 4 + r;
#pragma unroll
                for (int j = 0; j < 2; j++)
                    Xout[(size_t)gr * 256 + w * 32 + j * 16 + c] = xv[i][j][r];
            }
    }
}

// ---------------------------------------------------------------------------
// MFMA flash attention, key-split x2 (reverted from x4): part owns keys
// [part*1024, part*1024+1024) -> 8 supertiles/block, 1024 blocks (4/CU).
// ---------------------------------------------------------------------------
__global__ __launch_bounds__(256) void attn_kernel(
    const u16* __restrict__ QKV, const u16* __restrict__ VT,
    u16* __restrict__ PO, float* __restrict__ Lp)
{
    const int h = blockIdx.y, b = blockIdx.z;
    const int part = blockIdx.x & (KSPLIT - 1);
    const int q0 = (blockIdx.x >> 1) * 128;
    const int tid = threadIdx.x, w = tid >> 6, lane = tid & 63;
    const int c = lane & 15, quad = lane >> 4;

    __shared__ u16 Kf[4096];
    __shared__ u16 Vf[4096];

    const u16* qp = QKV + (size_t)(b * T_SEQ + q0 + w * 32 + c) * QKV_N + h * 32 + quad * 8;
    bf16x8 aQ0 = *(const bf16x8*)qp;
    bf16x8 aQ1 = *(const bf16x8*)(qp + 16 * QKV_N);

    const bf16x8 bOnes = {0x3F80, 0x3F80, 0x3F80, 0x3F80,
                          0x3F80, 0x3F80, 0x3F80, 0x3F80};

    f32x4 O[2][2] = {};
    f32x4 Ol0 = {0.f, 0.f, 0.f, 0.f}, Ol1 = {0.f, 0.f, 0.f, 0.f};

    const u16* kgp = QKV + (size_t)(b * T_SEQ + w * 16 + c) * QKV_N + 256 + h * 32 + quad * 8;
    const u16* vgp = VT + ((size_t)h * 32 + (lane & 31)) * M_ROWS + b * T_SEQ
                     + (w * 2 + (lane >> 5)) * 8;
    u16* kfw = Kf + w * 512 + lane * 8;

    const int vd  = lane & 31, vdh = vd >> 4, vc = vd & 15, vhi = lane >> 5;
    const int vkh = w >> 1, vseg = w & 1;
    const int voff = ((((vkh * 2 + vdh) * 4 + 2 * vhi) * 16 + vc) * 8) + vseg * 4;

    const int kbeg = part * (T_SEQ / KSPLIT);
    const int kend = kbeg + T_SEQ / KSPLIT;

    bf16x8 gK0 = *(const bf16x8*)(kgp + (size_t)kbeg * QKV_N);
    bf16x8 gK1 = *(const bf16x8*)(kgp + (size_t)(kbeg + 64) * QKV_N);
    bf16x8 gV0 = *(const bf16x8*)(vgp + kbeg);
    bf16x8 gV1 = *(const bf16x8*)(vgp + kbeg + 64);

    for (int k0 = kbeg; k0 < kend; k0 += 128) {
        __syncthreads();
        *(bf16x8*)kfw          = gK0;
        *(bf16x8*)(kfw + 2048) = gK1;
        {
            bf16x4 l0v = __builtin_shufflevector(gV0, gV0, 0, 1, 2, 3);
            bf16x4 h0v = __builtin_shufflevector(gV0, gV0, 4, 5, 6, 7);
            bf16x4 l1v = __builtin_shufflevector(gV1, gV1, 0, 1, 2, 3);
            bf16x4 h1v = __builtin_shufflevector(gV1, gV1, 4, 5, 6, 7);
            *(bf16x4*)&Vf[voff]              = l0v;
            *(bf16x4*)&Vf[voff + 128]        = h0v;
            *(bf16x4*)&Vf[2048 + voff]       = l1v;
            *(bf16x4*)&Vf[2048 + voff + 128] = h1v;
        }
        __syncthreads();
        if (k0 + 128 < kend) {
            gK0 = *(const bf16x8*)(kgp + (size_t)(k0 + 128) * QKV_N);
            gK1 = *(const bf16x8*)(kgp + (size_t)(k0 + 192) * QKV_N);
            gV0 = *(const bf16x8*)(vgp + k0 + 128);
            gV1 = *(const bf16x8*)(vgp + k0 + 192);
        }

#pragma unroll
        for (int hf = 0; hf < 2; hf++) {
            const u16* Kb = Kf + hf * 2048;
            const u16* Vb = Vf + hf * 2048;

            unsigned pk0[4][2], pk1[4][2];
#pragma unroll
            for (int g = 0; g < 4; g++) {
                bf16x8 aK = *(const bf16x8*)&Kb[g * 512 + lane * 8];
                f32x4 S0 = __builtin_amdgcn_mfma_f32_16x16x32_bf16(
                    aK, aQ0, (f32x4){0.f, 0.f, 0.f, 0.f}, 0, 0, 0);
                f32x4 S1 = __builtin_amdgcn_mfma_f32_16x16x32_bf16(
                    aK, aQ1, (f32x4){0.f, 0.f, 0.f, 0.f}, 0, 0, 0);
                pk0[g][0] = pack2bf(__builtin_amdgcn_exp2f(S0[0]),
                                    __builtin_amdgcn_exp2f(S0[1]));
                pk0[g][1] = pack2bf(__builtin_amdgcn_exp2f(S0[2]),
                                    __builtin_amdgcn_exp2f(S0[3]));
                pk1[g][0] = pack2bf(__builtin_amdgcn_exp2f(S1[0]),
                                    __builtin_amdgcn_exp2f(S1[1]));
                pk1[g][1] = pack2bf(__builtin_amdgcn_exp2f(S1[2]),
                                    __builtin_amdgcn_exp2f(S1[3]));
            }

            __builtin_amdgcn_s_setprio(1);
#pragma unroll
            for (int kh = 0; kh < 2; kh++) {
                bf16x8 aP0 = __builtin_bit_cast(bf16x8,
                    (u32x4){pk0[2 * kh][0], pk0[2 * kh][1],
                            pk0[2 * kh + 1][0], pk0[2 * kh + 1][1]});
                bf16x8 aP1 = __builtin_bit_cast(bf16x8,
                    (u32x4){pk1[2 * kh][0], pk1[2 * kh][1],
                            pk1[2 * kh + 1][0], pk1[2 * kh + 1][1]});
                Ol0 = __builtin_amdgcn_mfma_f32_16x16x32_bf16(aP0, bOnes, Ol0, 0, 0, 0);
                Ol1 = __builtin_amdgcn_mfma_f32_16x16x32_bf16(aP1, bOnes, Ol1, 0, 0, 0);
#pragma unroll
                for (int dh = 0; dh < 2; dh++) {
                    bf16x8 bV = *(const bf16x8*)&Vb[((kh * 2 + dh) * 64 + lane) * 8];
                    O[0][dh] = __builtin_amdgcn_mfma_f32_16x16x32_bf16(aP0, bV, O[0][dh], 0, 0, 0);
                    O[1][dh] = __builtin_amdgcn_mfma_f32_16x16x32_bf16(aP1, bV, O[1][dh], 0, 0, 0);
                }
            }
            __builtin_amdgcn_s_setprio(0);
        }
    }

    u16* pb = PO + (size_t)part * M_ROWS * 256
              + (size_t)(b * T_SEQ + q0 + w * 32) * 256 + h * 32;
    if (c == 0) {
        float* lb = Lp + (size_t)part * M_ROWS * 8
                    + (size_t)(b * T_SEQ + q0 + w * 32) * 8 + h;
#pragma unroll
        for (int r = 0; r < 4; r++) {
            lb[(size_t)(quad * 4 + r) * 8]      = Ol0[r];
            lb[(size_t)(16 + quad * 4 + r) * 8] = Ol1[r];
        }
    }
#pragma unroll
    for (int r = 0; r < 4; r++) {
        int src = quad * 4 + r;
        pb[(size_t)src * 256 + c]             = f2bf(O[0][0][r]);
        pb[(size_t)src * 256 + 16 + c]        = f2bf(O[0][1][r]);
        pb[(size_t)(16 + src) * 256 + c]      = f2bf(O[1][0][r]);
        pb[(size_t)(16 + src) * 256 + 16 + c] = f2bf(O[1][1][r]);
    }
}

// ---------------------------------------------------------------------------
extern "C" void kernel_launch(void* const* d_in, const int* in_sizes, int n_in,
                              void* d_out, int out_size, void* d_ws, size_t ws_size,
                              hipStream_t stream)
{
    const float* x     = (const float*)d_in[0];
    const float* ln1_s = (const float*)d_in[1];
    const float* ln1_b = (const float*)d_in[2];
    const float* wq    = (const float*)d_in[3];
    const float* bq    = (const float*)d_in[4];
    const float* wk    = (const float*)d_in[5];
    const float* bk    = (const float*)d_in[6];
    const float* wv    = (const float*)d_in[7];
    const float* bv    = (const float*)d_in[8];
    const float* wo    = (const float*)d_in[9];
    const float* bo    = (const float*)d_in[10];
    const float* ln2_s = (const float*)d_in[11];
    const float* ln2_b = (const float*)d_in[12];
    const float* w1    = (const float*)d_in[13];
    const float* b1    = (const float*)d_in[14];
    const float* w2    = (const float*)d_in[15];
    const float* b2    = (const float*)d_in[16];

    float* X = (float*)d_out;                   // fp32 residual stream

    u16* normed = (u16*)d_ws;                               // 8192*256
    u16* qkv    = normed + (size_t)M_ROWS * 256;            // 8192*768
    u16* PO2    = qkv + (size_t)M_ROWS * QKV_N;             // 2 x 8192*256
    u16* h1     = qkv;   // spans qkv+PO2[0]: 8192*1024 (PO2[0] consumed by then)
    u16* wqkv_t = PO2 + (size_t)KSPLIT * M_ROWS * 256;      // 6*768*256
    u16* wo_t   = wqkv_t + (size_t)N_LAYERSC * QKV_N * 256; // 6*256*256
    u16* w1_t   = wo_t + (size_t)N_LAYERSC * 256 * 256;     // 6*1024*256
    u16* w2_t   = w1_t + (size_t)N_LAYERSC * D_FFC * 256;   // 6*256*1024
    float* qkvb = (float*)(w2_t + (size_t)N_LAYERSC * 256 * D_FFC); // 6*768 fp32
    u16* VTb    = (u16*)(qkvb + N_LAYERSC * QKV_N);         // 256*8192
    float* Lp   = (float*)(VTb + (size_t)256 * M_ROWS);     // 2*8192*8 fp32

    dim3 blk(256), blk512(512);

    // ---- ALL weight prep + X=x + ln1(layer0) in one dispatch
    prep_all<<<dim3(4626 + M_ROWS / 4), blk, 0, stream>>>(
        wq, wk, wv, wo, w1, w2, bq, bk, bv,
        wqkv_t, wo_t, w1_t, w2_t, qkvb,
        x, ln1_s, ln1_b, X, normed);

    dim3 g_qkv(QKV_N / 128, M_ROWS / 128);              // (6,64)
    dim3 g_ff(D_FFC / 128, M_ROWS / 128);               // (8,64)
    dim3 g_ln32(M_ROWS / 32);                           // 256 blocks
    dim3 g_attn(KSPLIT * T_SEQ / 128, N_HEADSC, B_SZ);  // (32,8,4) = 1024 blocks

    for (int l = 0; l < N_LAYERSC; l++) {
        mfma_gemm<3><<<g_qkv, blk, 0, stream>>>(
            normed, wqkv_t + (size_t)l * QKV_N * 256, qkvb + l * QKV_N,
            VTb, qkv, QKV_N, 256);
        attn_kernel<<<g_attn, blk, 0, stream>>>(qkv, VTb, PO2, Lp);
        // Wo + resid + ln2, with the 2-way key-split merge fused into A-staging
        gemm_ln<1, 1><<<g_ln32, blk512, 0, stream>>>(
            PO2, Lp, wo_t + (size_t)l * 256 * 256, bo + l * 256, X,
            X, ln2_s + l * 256, ln2_b + l * 256, VTb, 256);
        mfma_gemm<2><<<g_ff, blk, 0, stream>>>(
            VTb, w1_t + (size_t)l * D_FFC * 256, b1 + l * D_FFC,
            nullptr, h1, D_FFC, 256);
        if (l + 1 < N_LAYERSC) {
            gemm_ln<1, 0><<<g_ln32, blk512, 0, stream>>>(
                h1, nullptr, w2_t + (size_t)l * 256 * D_FFC,
                b2 + l * 256, X, X, ln1_s + (l + 1) * 256,
                ln1_b + (l + 1) * 256, normed, D_FFC);
        } else {
            gemm_ln<0, 0><<<g_ln32, blk512, 0, stream>>>(
                h1, nullptr, w2_t + (size_t)l * 256 * D_FFC,
                b2 + l * 256, X, X, nullptr, nullptr, nullptr, D_FFC);
        }
    }
}

// Round 10
// 600.822 us; speedup vs baseline: 1.0416x; 1.0232x over previous
//
#include <hip/hip_runtime.h>
#include <math.h>

#define D_MODELC 256
#define N_LAYERSC 6
#define N_HEADSC 8
#define D_FFC 1024
#define HEAD_DIMC 32
#define B_SZ 4
#define T_SEQ 2048
#define M_ROWS 8192
#define QKV_N 768
#define KSPLIT 2

typedef short bf16x8 __attribute__((ext_vector_type(8)));
typedef short bf16x4 __attribute__((ext_vector_type(4)));
typedef float f32x4  __attribute__((ext_vector_type(4)));
typedef unsigned u32x4 __attribute__((ext_vector_type(4)));
typedef unsigned short u16;

// scale(1/sqrt(32)) * log2(e) folded into wq at conversion time
#define QSCALE 0.25503488f

// LDS XOR swizzle for 128B-row-stride tiles (rule #21: linear gload dest +
// pre-swizzled global source + swizzled read).
#define SWZ(b) ((b) ^ (((b) >> 3) & 0x70))

// direct global->LDS DMA, 16 bytes per lane (literal size required)
__device__ __forceinline__ void gload16(const void* g, void* l) {
    __builtin_amdgcn_global_load_lds(
        (const __attribute__((address_space(1))) void*)g,
        (__attribute__((address_space(3))) void*)l, 16, 0, 0);
}

__device__ __forceinline__ u16 f2bf(float x) {
    unsigned u = __builtin_bit_cast(unsigned, x);
    u += 0x7FFF + ((u >> 16) & 1);          // round-to-nearest-even
    return (u16)(u >> 16);
}

__device__ __forceinline__ float bf2f(short x) {
    return __builtin_bit_cast(float, (unsigned)((u16)x) << 16);
}

// packed bf16 pair (truncating) via single v_perm_b32: low16=a.hi, high16=b.hi
__device__ __forceinline__ unsigned pack2bf(float a, float b) {
    return __builtin_amdgcn_perm(__builtin_bit_cast(unsigned, b),
                                 __builtin_bit_cast(unsigned, a), 0x07060302u);
}

// A&S 7.1.26 erf (|err|<=1.5e-7), one v_exp + one v_rcp; exact-gelu drop-in.
__device__ __forceinline__ float fast_gelu(float x) {
    float y  = x * 0.70710678118654752f;
    float ay = __builtin_fabsf(y);
    float t  = __builtin_amdgcn_rcpf(1.0f + 0.3275911f * ay);
    float p  = t * (0.254829592f + t * (-0.284496736f + t * (1.421413741f
               + t * (-1.453152027f + t * 1.061405429f))));
    float e  = __builtin_amdgcn_exp2f(-ay * ay * 1.4426950408889634f);
    float er = 1.0f - p * e;
    er = y < 0.0f ? -er : er;
    return 0.5f * x * (1.0f + er);
}

// ---------------------------------------------------------------------------
// prep_all: ALL weight prep + ln_copy in ONE dispatch (unchanged).
// ---------------------------------------------------------------------------
__device__ __forceinline__ void transpose_tile(
    const float* __restrict__ src, u16* __restrict__ dst,
    int K, int N, int k0, int n0, float scale, float (*ts)[33])
{
    const int r = threadIdx.x >> 3, c4 = (threadIdx.x & 7) * 4;
    const float4 v = *(const float4*)(src + (size_t)(k0 + r) * N + n0 + c4);
    ts[r][c4 + 0] = v.x; ts[r][c4 + 1] = v.y;
    ts[r][c4 + 2] = v.z; ts[r][c4 + 3] = v.w;
    __syncthreads();
    bf16x4 o;
#pragma unroll
    for (int i = 0; i < 4; i++) o[i] = (short)f2bf(ts[c4 + i][r] * scale);
    *(bf16x4*)(dst + (size_t)(n0 + r) * K + k0 + c4) = o;
}

__global__ __launch_bounds__(256) void prep_all(
    const float* __restrict__ wq, const float* __restrict__ wk,
    const float* __restrict__ wv, const float* __restrict__ wo,
    const float* __restrict__ w1, const float* __restrict__ w2,
    const float* __restrict__ bq, const float* __restrict__ bk,
    const float* __restrict__ bv,
    u16* __restrict__ wqkv_t, u16* __restrict__ wo_t,
    u16* __restrict__ w1_t, u16* __restrict__ w2_t,
    float* __restrict__ qkvb,
    const float* __restrict__ x, const float* __restrict__ gamma,
    const float* __restrict__ beta, float* __restrict__ X,
    u16* __restrict__ Y)
{
    __shared__ float ts[32][33];
    const int bid = blockIdx.x;
    if (bid < 1152) {                 // wq/wk/wv: 3 x 6 x 64 tiles
        const int sec = bid / 384, t = bid % 384;
        const int z = t >> 6, rem = t & 63, ty = rem >> 3, tx = rem & 7;
        const float* src = sec == 0 ? wq : (sec == 1 ? wk : wv);
        transpose_tile(src + (size_t)z * 65536,
                       wqkv_t + (size_t)z * QKV_N * 256 + sec * 256 * 256,
                       256, 256, ty * 32, tx * 32,
                       sec == 0 ? QSCALE : 1.0f, ts);
    } else if (bid < 1536) {          // wo
        const int t = bid - 1152;
        const int z = t >> 6, rem = t & 63, ty = rem >> 3, tx = rem & 7;
        transpose_tile(wo + (size_t)z * 65536, wo_t + (size_t)z * 65536,
                       256, 256, ty * 32, tx * 32, 1.0f, ts);
    } else if (bid < 3072) {          // w1: K=256, N=1024, 6 x 256 tiles
        const int t = bid - 1536;
        const int z = t >> 8, rem = t & 255, ty = rem >> 5, tx = rem & 31;
        transpose_tile(w1 + (size_t)z * 262144, w1_t + (size_t)z * 262144,
                       256, D_FFC, ty * 32, tx * 32, 1.0f, ts);
    } else if (bid < 4608) {          // w2: K=1024, N=256
        const int t = bid - 3072;
        const int z = t >> 8, rem = t & 255, ty = rem >> 3, tx = rem & 7;
        transpose_tile(w2 + (size_t)z * 262144, w2_t + (size_t)z * 262144,
                       D_FFC, 256, ty * 32, tx * 32, 1.0f, ts);
    } else if (bid < 4626) {          // fused qkv bias
        const int i = (bid - 4608) * 256 + threadIdx.x;
        const int l = i / QKV_N, j = i % QKV_N;
        float v;
        if (j < 256)      v = bq[l * 256 + j] * QSCALE;
        else if (j < 512) v = bk[l * 256 + j - 256];
        else              v = bv[l * 256 + j - 512];
        qkvb[i] = v;
    } else {                          // X = x; Y = bf16(LN1_0(x))
        const int w = threadIdx.x >> 6, lane = threadIdx.x & 63;
        const int row = (bid - 4626) * 4 + w;
        const float4 v = *(const float4*)(x + (size_t)row * 256 + lane * 4);
        *(float4*)(X + (size_t)row * 256 + lane * 4) = v;
        float sum = v.x + v.y + v.z + v.w;
        float sq  = v.x * v.x + v.y * v.y + v.z * v.z + v.w * v.w;
#pragma unroll
        for (int off = 32; off > 0; off >>= 1) {
            sum += __shfl_xor(sum, off, 64);
            sq  += __shfl_xor(sq,  off, 64);
        }
        float mu  = sum * (1.0f / 256.0f);
        float var = sq * (1.0f / 256.0f) - mu * mu;
        float rr  = rsqrtf(var + 1e-5f);
        const float4 g  = *(const float4*)(gamma + lane * 4);
        const float4 bb = *(const float4*)(beta + lane * 4);
        bf16x4 o;
        o[0] = (short)f2bf((v.x - mu) * rr * g.x + bb.x);
        o[1] = (short)f2bf((v.y - mu) * rr * g.y + bb.y);
        o[2] = (short)f2bf((v.z - mu) * rr * g.z + bb.z);
        o[3] = (short)f2bf((v.w - mu) * rr * g.w + bb.w);
        *(bf16x4*)(Y + (size_t)row * 256 + lane * 4) = o;
    }
}

// ---------------------------------------------------------------------------
// MFMA GEMM, 128x128 tile, BK=64, global_load_lds staging (unchanged).
// ---------------------------------------------------------------------------
template <int EPI>
__global__ __launch_bounds__(256) void mfma_gemm(
    const u16* __restrict__ A, const u16* __restrict__ Bt,
    const float* __restrict__ bias, u16* __restrict__ Vout,
    void* __restrict__ Cout, int N, int K)
{
    __shared__ u16 As[128 * 64];
    __shared__ u16 Bs[128 * 64];
    const int tid = threadIdx.x, w = tid >> 6, lane = tid & 63;
    const int c = lane & 15, quad = lane >> 4;
    const int row0 = blockIdx.y * 128, col0 = blockIdx.x * 128;
    const int wr = w >> 1, wc = w & 1;
    const int cswz = (c & 7) << 4;

    int flv[4], rA[4], colA[4];
#pragma unroll
    for (int ci = 0; ci < 4; ci++) {
        flv[ci]  = (w * 4 + ci) * 1024 + lane * 16;
        const int fsw = SWZ(flv[ci]);
        rA[ci]   = fsw >> 7;
        colA[ci] = (fsw & 127) >> 1;
    }

    f32x4 acc[4][4] = {};

    for (int k0 = 0; k0 < K; k0 += 64) {
        __syncthreads();
#pragma unroll
        for (int ci = 0; ci < 4; ci++) {
            gload16(A  + (size_t)(row0 + rA[ci]) * K + k0 + colA[ci],
                    (char*)As + flv[ci]);
            gload16(Bt + (size_t)(col0 + rA[ci]) * K + k0 + colA[ci],
                    (char*)Bs + flv[ci]);
        }
        __syncthreads();
#pragma unroll
        for (int kk = 0; kk < 2; kk++) {
            bf16x8 af[4], bfv[4];
#pragma unroll
            for (int i = 0; i < 4; i++)
                af[i] = *(const bf16x8*)((const char*)As +
                    ((((wr * 64 + i * 16 + c) * 64 + kk * 32 + quad * 8) * 2) ^ cswz));
#pragma unroll
            for (int j = 0; j < 4; j++)
                bfv[j] = *(const bf16x8*)((const char*)Bs +
                    ((((wc * 64 + j * 16 + c) * 64 + kk * 32 + quad * 8) * 2) ^ cswz));
#pragma unroll
            for (int i = 0; i < 4; i++)
#pragma unroll
                for (int j = 0; j < 4; j++)
                    acc[i][j] = __builtin_amdgcn_mfma_f32_16x16x32_bf16(
                        af[i], bfv[j], acc[i][j], 0, 0, 0);
        }
    }

    float bj[4];
#pragma unroll
    for (int j = 0; j < 4; j++) bj[j] = bias[col0 + wc * 64 + j * 16 + c];

    if (EPI == 3 && col0 >= 512) {
#pragma unroll
        for (int i = 0; i < 4; i++) {
            const int tok = row0 + wr * 64 + i * 16 + quad * 4;
#pragma unroll
            for (int j = 0; j < 4; j++) {
                const int dim = col0 - 512 + wc * 64 + j * 16 + c;
                bf16x4 o;
#pragma unroll
                for (int r = 0; r < 4; r++) o[r] = (short)f2bf(acc[i][j][r] + bj[j]);
                *(bf16x4*)&Vout[(size_t)dim * M_ROWS + tok] = o;
            }
        }
        return;
    }

#pragma unroll
    for (int i = 0; i < 4; i++) {
#pragma unroll
        for (int r = 0; r < 4; r++) {
            const int gr = row0 + wr * 64 + i * 16 + quad * 4 + r;
#pragma unroll
            for (int j = 0; j < 4; j++) {
                const int gc = col0 + wc * 64 + j * 16 + c;
                float v = acc[i][j][r] + bj[j];
                if (EPI == 2) v = fast_gelu(v);
                ((u16*)Cout)[(size_t)gr * N + gc] = f2bf(v);
            }
        }
    }
}

// ---------------------------------------------------------------------------
// GEMM (N=256, BM=16, BN=256) + residual + optional fused LayerNorm.
// BM 32->16: grid doubles to 512 blocks = 2 independent barrier domains per
// CU, so one block's staging drain overlaps the other's MFMA phase (R9's
// 8-wave single-domain variant proved lockstep waves don't overlap drains).
// MERGE=1: 2-way key-split partials merged inline during A staging.
// ---------------------------------------------------------------------------
template <int DOLN, int MERGE>
__global__ __launch_bounds__(256) void gemm_ln(
    const u16* __restrict__ A, const float* __restrict__ Lmrg,
    const u16* __restrict__ Bt, const float* __restrict__ bias,
    const float* __restrict__ resid, float* __restrict__ Xout,
    const float* __restrict__ gamma, const float* __restrict__ beta,
    u16* __restrict__ Nout, int K)
{
    __shared__ u16 As[16 * 64];                 // 2 KB
    __shared__ u16 Bs[256 * 64];                // 32 KB
    __shared__ float2 red[4][16];
    const int tid = threadIdx.x, w = tid >> 6, lane = tid & 63;
    const int c = lane & 15, quad = lane >> 4;
    const int row0 = blockIdx.x * 16;
    const int cswz = (c & 7) << 4;

    // A staging: 2 KB staged by tid<128, 16B each
    const int flA  = tid * 16;                  // valid for tid<128
    const bool doA = tid < 128;
    const int fsA  = SWZ(flA);
    const int rA_m = flA >> 7, colA_m = (flA & 127) >> 1;   // MERGE reg-path
    const int rA_g = fsA >> 7, colA_g = (fsA & 127) >> 1;   // gload path

    // B staging: 32 KB, 8 x 16B per thread
    int flB[8], rB[8], colB[8];
#pragma unroll
    for (int ci = 0; ci < 8; ci++) {
        flB[ci]  = (w * 8 + ci) * 1024 + lane * 16;
        const int fsB = SWZ(flB[ci]);
        rB[ci]   = fsB >> 7;
        colB[ci] = (fsB & 127) >> 1;
    }

    f32x4 acc[4] = {};

    auto loadA = [&](int gc) -> bf16x8 {
        const int row = row0 + rA_m;
        const int head = gc >> 5;
        float ls = 0.f;
#pragma unroll
        for (int p = 0; p < KSPLIT; p++)
            ls += Lmrg[(size_t)p * M_ROWS * 8 + (size_t)row * 8 + head];
        const float inv = __builtin_amdgcn_rcpf(ls);
        float s[8] = {0.f, 0.f, 0.f, 0.f, 0.f, 0.f, 0.f, 0.f};
#pragma unroll
        for (int p = 0; p < KSPLIT; p++) {
            bf16x8 a = *(const bf16x8*)(A + (size_t)p * M_ROWS * 256
                                          + (size_t)row * 256 + gc);
#pragma unroll
            for (int j = 0; j < 8; j++) s[j] += bf2f(a[j]);
        }
        bf16x8 o;
#pragma unroll
        for (int j = 0; j < 8; j++) o[j] = (short)f2bf(s[j] * inv);
        return o;
    };

    bf16x8 pA;
    if (MERGE && doA) pA = loadA(colA_m);

    for (int k0 = 0; k0 < K; k0 += 64) {
        __syncthreads();
#pragma unroll
        for (int ci = 0; ci < 8; ci++)
            gload16(Bt + (size_t)rB[ci] * K + k0 + colB[ci], (char*)Bs + flB[ci]);
        if (MERGE) {
            if (doA) *(bf16x8*)((char*)As + fsA) = pA;
        } else {
            if (doA) gload16(A + (size_t)(row0 + rA_g) * K + k0 + colA_g,
                             (char*)As + flA);
        }
        __syncthreads();
        if (MERGE && doA && k0 + 64 < K)
            pA = loadA(k0 + 64 + colA_m);   // lands during compute
#pragma unroll
        for (int kk = 0; kk < 2; kk++) {
            bf16x8 af, bfv[4];
            af = *(const bf16x8*)((const char*)As +
                (((c * 64 + kk * 32 + quad * 8) * 2) ^ cswz));
#pragma unroll
            for (int j = 0; j < 4; j++)
                bfv[j] = *(const bf16x8*)((const char*)Bs +
                    ((((w * 64 + j * 16 + c) * 64 + kk * 32 + quad * 8) * 2) ^ cswz));
#pragma unroll
            for (int j = 0; j < 4; j++)
                acc[j] = __builtin_amdgcn_mfma_f32_16x16x32_bf16(
                    af, bfv[j], acc[j], 0, 0, 0);
        }
    }

    float bj[4];
#pragma unroll
    for (int j = 0; j < 4; j++) bj[j] = bias[w * 64 + j * 16 + c];
    float xv[4][4];
#pragma unroll
    for (int r = 0; r < 4; r++) {
        const int gr = row0 + quad * 4 + r;
#pragma unroll
        for (int j = 0; j < 4; j++) {
            const int gc = w * 64 + j * 16 + c;
            xv[j][r] = acc[j][r] + bj[j] + resid[(size_t)gr * 256 + gc];
        }
    }

    if (DOLN) {
        float sm[4], sp[4];
#pragma unroll
        for (int r = 0; r < 4; r++) {
            float s = 0.f, q = 0.f;
#pragma unroll
            for (int j = 0; j < 4; j++) { s += xv[j][r]; q += xv[j][r] * xv[j][r]; }
            sm[r] = s; sp[r] = q;
        }
#pragma unroll
        for (int off = 1; off < 16; off <<= 1)
#pragma unroll
            for (int r = 0; r < 4; r++) {
                sm[r] += __shfl_xor(sm[r], off, 64);
                sp[r] += __shfl_xor(sp[r], off, 64);
            }
        __syncthreads();
        if (c == 0) {
#pragma unroll
            for (int r = 0; r < 4; r++)
                red[w][quad * 4 + r] = make_float2(sm[r], sp[r]);
        }
        __syncthreads();
#pragma unroll
        for (int r = 0; r < 4; r++) {
            const int row = quad * 4 + r;
            float2 t0 = red[0][row], t1 = red[1][row];
            float2 t2 = red[2][row], t3 = red[3][row];
            float S = (t0.x + t1.x) + (t2.x + t3.x);
            float Q = (t0.y + t1.y) + (t2.y + t3.y);
            float mu = S * (1.0f / 256.0f);
            float var = Q * (1.0f / 256.0f) - mu * mu;
            float rr = rsqrtf(var + 1e-5f);
            const int gr = row0 + row;
#pragma unroll
            for (int j = 0; j < 4; j++) {
                const int gc = w * 64 + j * 16 + c;
                float x = xv[j][r];
                Xout[(size_t)gr * 256 + gc] = x;
                Nout[(size_t)gr * 256 + gc] =
                    f2bf((x - mu) * rr * gamma[gc] + beta[gc]);
            }
        }
    } else {
#pragma unroll
        for (int r = 0; r < 4; r++) {
            const int gr = row0 + quad * 4 + r;
#pragma unroll
            for (int j = 0; j < 4; j++)
                Xout[(size_t)gr * 256 + w * 64 + j * 16 + c] = xv[j][r];
        }
    }
}

// ---------------------------------------------------------------------------
// MFMA flash attention, key-split x2 (unchanged from R9).
// ---------------------------------------------------------------------------
__global__ __launch_bounds__(256) void attn_kernel(
    const u16* __restrict__ QKV, const u16* __restrict__ VT,
    u16* __restrict__ PO, float* __restrict__ Lp)
{
    const int h = blockIdx.y, b = blockIdx.z;
    const int part = blockIdx.x & (KSPLIT - 1);
    const int q0 = (blockIdx.x >> 1) * 128;
    const int tid = threadIdx.x, w = tid >> 6, lane = tid & 63;
    const int c = lane & 15, quad = lane >> 4;

    __shared__ u16 Kf[4096];
    __shared__ u16 Vf[4096];

    const u16* qp = QKV + (size_t)(b * T_SEQ + q0 + w * 32 + c) * QKV_N + h * 32 + quad * 8;
    bf16x8 aQ0 = *(const bf16x8*)qp;
    bf16x8 aQ1 = *(const bf16x8*)(qp + 16 * QKV_N);

    const bf16x8 bOnes = {0x3F80, 0x3F80, 0x3F80, 0x3F80,
                          0x3F80, 0x3F80, 0x3F80, 0x3F80};

    f32x4 O[2][2] = {};
    f32x4 Ol0 = {0.f, 0.f, 0.f, 0.f}, Ol1 = {0.f, 0.f, 0.f, 0.f};

    const u16* kgp = QKV + (size_t)(b * T_SEQ + w * 16 + c) * QKV_N + 256 + h * 32 + quad * 8;
    const u16* vgp = VT + ((size_t)h * 32 + (lane & 31)) * M_ROWS + b * T_SEQ
                     + (w * 2 + (lane >> 5)) * 8;
    u16* kfw = Kf + w * 512 + lane * 8;

    const int vd  = lane & 31, vdh = vd >> 4, vc = vd & 15, vhi = lane >> 5;
    const int vkh = w >> 1, vseg = w & 1;
    const int voff = ((((vkh * 2 + vdh) * 4 + 2 * vhi) * 16 + vc) * 8) + vseg * 4;

    const int kbeg = part * (T_SEQ / KSPLIT);
    const int kend = kbeg + T_SEQ / KSPLIT;

    bf16x8 gK0 = *(const bf16x8*)(kgp + (size_t)kbeg * QKV_N);
    bf16x8 gK1 = *(const bf16x8*)(kgp + (size_t)(kbeg + 64) * QKV_N);
    bf16x8 gV0 = *(const bf16x8*)(vgp + kbeg);
    bf16x8 gV1 = *(const bf16x8*)(vgp + kbeg + 64);

    for (int k0 = kbeg; k0 < kend; k0 += 128) {
        __syncthreads();
        *(bf16x8*)kfw          = gK0;
        *(bf16x8*)(kfw + 2048) = gK1;
        {
            bf16x4 l0v = __builtin_shufflevector(gV0, gV0, 0, 1, 2, 3);
            bf16x4 h0v = __builtin_shufflevector(gV0, gV0, 4, 5, 6, 7);
            bf16x4 l1v = __builtin_shufflevector(gV1, gV1, 0, 1, 2, 3);
            bf16x4 h1v = __builtin_shufflevector(gV1, gV1, 4, 5, 6, 7);
            *(bf16x4*)&Vf[voff]              = l0v;
            *(bf16x4*)&Vf[voff + 128]        = h0v;
            *(bf16x4*)&Vf[2048 + voff]       = l1v;
            *(bf16x4*)&Vf[2048 + voff + 128] = h1v;
        }
        __syncthreads();
        if (k0 + 128 < kend) {
            gK0 = *(const bf16x8*)(kgp + (size_t)(k0 + 128) * QKV_N);
            gK1 = *(const bf16x8*)(kgp + (size_t)(k0 + 192) * QKV_N);
            gV0 = *(const bf16x8*)(vgp + k0 + 128);
            gV1 = *(const bf16x8*)(vgp + k0 + 192);
        }

#pragma unroll
        for (int hf = 0; hf < 2; hf++) {
            const u16* Kb = Kf + hf * 2048;
            const u16* Vb = Vf + hf * 2048;

            unsigned pk0[4][2], pk1[4][2];
#pragma unroll
            for (int g = 0; g < 4; g++) {
                bf16x8 aK = *(const bf16x8*)&Kb[g * 512 + lane * 8];
                f32x4 S0 = __builtin_amdgcn_mfma_f32_16x16x32_bf16(
                    aK, aQ0, (f32x4){0.f, 0.f, 0.f, 0.f}, 0, 0, 0);
                f32x4 S1 = __builtin_amdgcn_mfma_f32_16x16x32_bf16(
                    aK, aQ1, (f32x4){0.f, 0.f, 0.f, 0.f}, 0, 0, 0);
                pk0[g][0] = pack2bf(__builtin_amdgcn_exp2f(S0[0]),
                                    __builtin_amdgcn_exp2f(S0[1]));
                pk0[g][1] = pack2bf(__builtin_amdgcn_exp2f(S0[2]),
                                    __builtin_amdgcn_exp2f(S0[3]));
                pk1[g][0] = pack2bf(__builtin_amdgcn_exp2f(S1[0]),
                                    __builtin_amdgcn_exp2f(S1[1]));
                pk1[g][1] = pack2bf(__builtin_amdgcn_exp2f(S1[2]),
                                    __builtin_amdgcn_exp2f(S1[3]));
            }

            __builtin_amdgcn_s_setprio(1);
#pragma unroll
            for (int kh = 0; kh < 2; kh++) {
                bf16x8 aP0 = __builtin_bit_cast(bf16x8,
                    (u32x4){pk0[2 * kh][0], pk0[2 * kh][1],
                            pk0[2 * kh + 1][0], pk0[2 * kh + 1][1]});
                bf16x8 aP1 = __builtin_bit_cast(bf16x8,
                    (u32x4){pk1[2 * kh][0], pk1[2 * kh][1],
                            pk1[2 * kh + 1][0], pk1[2 * kh + 1][1]});
                Ol0 = __builtin_amdgcn_mfma_f32_16x16x32_bf16(aP0, bOnes, Ol0, 0, 0, 0);
                Ol1 = __builtin_amdgcn_mfma_f32_16x16x32_bf16(aP1, bOnes, Ol1, 0, 0, 0);
#pragma unroll
                for (int dh = 0; dh < 2; dh++) {
                    bf16x8 bV = *(const bf16x8*)&Vb[((kh * 2 + dh) * 64 + lane) * 8];
                    O[0][dh] = __builtin_amdgcn_mfma_f32_16x16x32_bf16(aP0, bV, O[0][dh], 0, 0, 0);
                    O[1][dh] = __builtin_amdgcn_mfma_f32_16x16x32_bf16(aP1, bV, O[1][dh], 0, 0, 0);
                }
            }
            __builtin_amdgcn_s_setprio(0);
        }
    }

    u16* pb = PO + (size_t)part * M_ROWS * 256
              + (size_t)(b * T_SEQ + q0 + w * 32) * 256 + h * 32;
    if (c == 0) {
        float* lb = Lp + (size_t)part * M_ROWS * 8
                    + (size_t)(b * T_SEQ + q0 + w * 32) * 8 + h;
#pragma unroll
        for (int r = 0; r < 4; r++) {
            lb[(size_t)(quad * 4 + r) * 8]      = Ol0[r];
            lb[(size_t)(16 + quad * 4 + r) * 8] = Ol1[r];
        }
    }
#pragma unroll
    for (int r = 0; r < 4; r++) {
        int src = quad * 4 + r;
        pb[(size_t)src * 256 + c]             = f2bf(O[0][0][r]);
        pb[(size_t)src * 256 + 16 + c]        = f2bf(O[0][1][r]);
        pb[(size_t)(16 + src) * 256 + c]      = f2bf(O[1][0][r]);
        pb[(size_t)(16 + src) * 256 + 16 + c] = f2bf(O[1][1][r]);
    }
}

// ---------------------------------------------------------------------------
extern "C" void kernel_launch(void* const* d_in, const int* in_sizes, int n_in,
                              void* d_out, int out_size, void* d_ws, size_t ws_size,
                              hipStream_t stream)
{
    const float* x     = (const float*)d_in[0];
    const float* ln1_s = (const float*)d_in[1];
    const float* ln1_b = (const float*)d_in[2];
    const float* wq    = (const float*)d_in[3];
    const float* bq    = (const float*)d_in[4];
    const float* wk    = (const float*)d_in[5];
    const float* bk    = (const float*)d_in[6];
    const float* wv    = (const float*)d_in[7];
    const float* bv    = (const float*)d_in[8];
    const float* wo    = (const float*)d_in[9];
    const float* bo    = (const float*)d_in[10];
    const float* ln2_s = (const float*)d_in[11];
    const float* ln2_b = (const float*)d_in[12];
    const float* w1    = (const float*)d_in[13];
    const float* b1    = (const float*)d_in[14];
    const float* w2    = (const float*)d_in[15];
    const float* b2    = (const float*)d_in[16];

    float* X = (float*)d_out;                   // fp32 residual stream

    u16* normed = (u16*)d_ws;                               // 8192*256
    u16* qkv    = normed + (size_t)M_ROWS * 256;            // 8192*768
    u16* PO2    = qkv + (size_t)M_ROWS * QKV_N;             // 2 x 8192*256
    u16* h1     = qkv;   // spans qkv+PO2[0]: 8192*1024 (PO2[0] consumed by then)
    u16* wqkv_t = PO2 + (size_t)KSPLIT * M_ROWS * 256;      // 6*768*256
    u16* wo_t   = wqkv_t + (size_t)N_LAYERSC * QKV_N * 256; // 6*256*256
    u16* w1_t   = wo_t + (size_t)N_LAYERSC * 256 * 256;     // 6*1024*256
    u16* w2_t   = w1_t + (size_t)N_LAYERSC * D_FFC * 256;   // 6*256*1024
    float* qkvb = (float*)(w2_t + (size_t)N_LAYERSC * 256 * D_FFC); // 6*768 fp32
    u16* VTb    = (u16*)(qkvb + N_LAYERSC * QKV_N);         // 256*8192
    float* Lp   = (float*)(VTb + (size_t)256 * M_ROWS);     // 2*8192*8 fp32

    dim3 blk(256);

    // ---- ALL weight prep + X=x + ln1(layer0) in one dispatch
    prep_all<<<dim3(4626 + M_ROWS / 4), blk, 0, stream>>>(
        wq, wk, wv, wo, w1, w2, bq, bk, bv,
        wqkv_t, wo_t, w1_t, w2_t, qkvb,
        x, ln1_s, ln1_b, X, normed);

    dim3 g_qkv(QKV_N / 128, M_ROWS / 128);              // (6,64)
    dim3 g_ff(D_FFC / 128, M_ROWS / 128);               // (8,64)
    dim3 g_ln16(M_ROWS / 16);                           // 512 blocks = 2/CU
    dim3 g_attn(KSPLIT * T_SEQ / 128, N_HEADSC, B_SZ);  // (32,8,4) = 1024 blocks

    for (int l = 0; l < N_LAYERSC; l++) {
        mfma_gemm<3><<<g_qkv, blk, 0, stream>>>(
            normed, wqkv_t + (size_t)l * QKV_N * 256, qkvb + l * QKV_N,
            VTb, qkv, QKV_N, 256);
        attn_kernel<<<g_attn, blk, 0, stream>>>(qkv, VTb, PO2, Lp);
        // Wo + resid + ln2, with the 2-way key-split merge fused into A-staging
        gemm_ln<1, 1><<<g_ln16, blk, 0, stream>>>(
            PO2, Lp, wo_t + (size_t)l * 256 * 256, bo + l * 256, X,
            X, ln2_s + l * 256, ln2_b + l * 256, VTb, 256);
        mfma_gemm<2><<<g_ff, blk, 0, stream>>>(
            VTb, w1_t + (size_t)l * D_FFC * 256, b1 + l * D_FFC,
            nullptr, h1, D_FFC, 256);
        if (l + 1 < N_LAYERSC) {
            gemm_ln<1, 0><<<g_ln16, blk, 0, stream>>>(
                h1, nullptr, w2_t + (size_t)l * 256 * D_FFC,
                b2 + l * 256, X, X, ln1_s + (l + 1) * 256,
                ln1_b + (l + 1) * 256, normed, D_FFC);
        } else {
            gemm_ln<0, 0><<<g_ln16, blk, 0, stream>>>(
                h1, nullptr, w2_t + (size_t)l * 256 * D_FFC,
                b2 + l * 256, X, X, nullptr, nullptr, nullptr, D_FFC);
        }
    }
}

// Round 11
// 581.121 us; speedup vs baseline: 1.0769x; 1.0339x over previous
//
#include <hip/hip_runtime.h>
#include <math.h>

#define D_MODELC 256
#define N_LAYERSC 6
#define N_HEADSC 8
#define D_FFC 1024
#define HEAD_DIMC 32
#define B_SZ 4
#define T_SEQ 2048
#define M_ROWS 8192
#define QKV_N 768
#define KSPLIT 2

typedef short bf16x8 __attribute__((ext_vector_type(8)));
typedef short bf16x4 __attribute__((ext_vector_type(4)));
typedef float f32x4  __attribute__((ext_vector_type(4)));
typedef unsigned u32x4 __attribute__((ext_vector_type(4)));
typedef unsigned short u16;

// scale(1/sqrt(32)) * log2(e) folded into wq at conversion time
#define QSCALE 0.25503488f

// LDS XOR swizzle for 128B-row-stride tiles (rule #21: linear gload dest +
// pre-swizzled global source + swizzled read).
#define SWZ(b) ((b) ^ (((b) >> 3) & 0x70))

// direct global->LDS DMA, 16 bytes per lane (literal size required)
__device__ __forceinline__ void gload16(const void* g, void* l) {
    __builtin_amdgcn_global_load_lds(
        (const __attribute__((address_space(1))) void*)g,
        (__attribute__((address_space(3))) void*)l, 16, 0, 0);
}

__device__ __forceinline__ u16 f2bf(float x) {
    unsigned u = __builtin_bit_cast(unsigned, x);
    u += 0x7FFF + ((u >> 16) & 1);          // round-to-nearest-even
    return (u16)(u >> 16);
}

__device__ __forceinline__ float bf2f(short x) {
    return __builtin_bit_cast(float, (unsigned)((u16)x) << 16);
}

// packed bf16 pair (truncating) via single v_perm_b32: low16=a.hi, high16=b.hi
__device__ __forceinline__ unsigned pack2bf(float a, float b) {
    return __builtin_amdgcn_perm(__builtin_bit_cast(unsigned, b),
                                 __builtin_bit_cast(unsigned, a), 0x07060302u);
}

// A&S 7.1.26 erf (|err|<=1.5e-7), one v_exp + one v_rcp; exact-gelu drop-in.
__device__ __forceinline__ float fast_gelu(float x) {
    float y  = x * 0.70710678118654752f;
    float ay = __builtin_fabsf(y);
    float t  = __builtin_amdgcn_rcpf(1.0f + 0.3275911f * ay);
    float p  = t * (0.254829592f + t * (-0.284496736f + t * (1.421413741f
               + t * (-1.453152027f + t * 1.061405429f))));
    float e  = __builtin_amdgcn_exp2f(-ay * ay * 1.4426950408889634f);
    float er = 1.0f - p * e;
    er = y < 0.0f ? -er : er;
    return 0.5f * x * (1.0f + er);
}

// ---------------------------------------------------------------------------
// prep_all: ALL weight prep + ln_copy in ONE dispatch (unchanged).
// ---------------------------------------------------------------------------
__device__ __forceinline__ void transpose_tile(
    const float* __restrict__ src, u16* __restrict__ dst,
    int K, int N, int k0, int n0, float scale, float (*ts)[33])
{
    const int r = threadIdx.x >> 3, c4 = (threadIdx.x & 7) * 4;
    const float4 v = *(const float4*)(src + (size_t)(k0 + r) * N + n0 + c4);
    ts[r][c4 + 0] = v.x; ts[r][c4 + 1] = v.y;
    ts[r][c4 + 2] = v.z; ts[r][c4 + 3] = v.w;
    __syncthreads();
    bf16x4 o;
#pragma unroll
    for (int i = 0; i < 4; i++) o[i] = (short)f2bf(ts[c4 + i][r] * scale);
    *(bf16x4*)(dst + (size_t)(n0 + r) * K + k0 + c4) = o;
}

__global__ __launch_bounds__(256) void prep_all(
    const float* __restrict__ wq, const float* __restrict__ wk,
    const float* __restrict__ wv, const float* __restrict__ wo,
    const float* __restrict__ w1, const float* __restrict__ w2,
    const float* __restrict__ bq, const float* __restrict__ bk,
    const float* __restrict__ bv,
    u16* __restrict__ wqkv_t, u16* __restrict__ wo_t,
    u16* __restrict__ w1_t, u16* __restrict__ w2_t,
    float* __restrict__ qkvb,
    const float* __restrict__ x, const float* __restrict__ gamma,
    const float* __restrict__ beta, float* __restrict__ X,
    u16* __restrict__ Y)
{
    __shared__ float ts[32][33];
    const int bid = blockIdx.x;
    if (bid < 1152) {                 // wq/wk/wv: 3 x 6 x 64 tiles
        const int sec = bid / 384, t = bid % 384;
        const int z = t >> 6, rem = t & 63, ty = rem >> 3, tx = rem & 7;
        const float* src = sec == 0 ? wq : (sec == 1 ? wk : wv);
        transpose_tile(src + (size_t)z * 65536,
                       wqkv_t + (size_t)z * QKV_N * 256 + sec * 256 * 256,
                       256, 256, ty * 32, tx * 32,
                       sec == 0 ? QSCALE : 1.0f, ts);
    } else if (bid < 1536) {          // wo
        const int t = bid - 1152;
        const int z = t >> 6, rem = t & 63, ty = rem >> 3, tx = rem & 7;
        transpose_tile(wo + (size_t)z * 65536, wo_t + (size_t)z * 65536,
                       256, 256, ty * 32, tx * 32, 1.0f, ts);
    } else if (bid < 3072) {          // w1: K=256, N=1024, 6 x 256 tiles
        const int t = bid - 1536;
        const int z = t >> 8, rem = t & 255, ty = rem >> 5, tx = rem & 31;
        transpose_tile(w1 + (size_t)z * 262144, w1_t + (size_t)z * 262144,
                       256, D_FFC, ty * 32, tx * 32, 1.0f, ts);
    } else if (bid < 4608) {          // w2: K=1024, N=256
        const int t = bid - 3072;
        const int z = t >> 8, rem = t & 255, ty = rem >> 3, tx = rem & 7;
        transpose_tile(w2 + (size_t)z * 262144, w2_t + (size_t)z * 262144,
                       D_FFC, 256, ty * 32, tx * 32, 1.0f, ts);
    } else if (bid < 4626) {          // fused qkv bias
        const int i = (bid - 4608) * 256 + threadIdx.x;
        const int l = i / QKV_N, j = i % QKV_N;
        float v;
        if (j < 256)      v = bq[l * 256 + j] * QSCALE;
        else if (j < 512) v = bk[l * 256 + j - 256];
        else              v = bv[l * 256 + j - 512];
        qkvb[i] = v;
    } else {                          // X = x; Y = bf16(LN1_0(x))
        const int w = threadIdx.x >> 6, lane = threadIdx.x & 63;
        const int row = (bid - 4626) * 4 + w;
        const float4 v = *(const float4*)(x + (size_t)row * 256 + lane * 4);
        *(float4*)(X + (size_t)row * 256 + lane * 4) = v;
        float sum = v.x + v.y + v.z + v.w;
        float sq  = v.x * v.x + v.y * v.y + v.z * v.z + v.w * v.w;
#pragma unroll
        for (int off = 32; off > 0; off >>= 1) {
            sum += __shfl_xor(sum, off, 64);
            sq  += __shfl_xor(sq,  off, 64);
        }
        float mu  = sum * (1.0f / 256.0f);
        float var = sq * (1.0f / 256.0f) - mu * mu;
        float rr  = rsqrtf(var + 1e-5f);
        const float4 g  = *(const float4*)(gamma + lane * 4);
        const float4 bb = *(const float4*)(beta + lane * 4);
        bf16x4 o;
        o[0] = (short)f2bf((v.x - mu) * rr * g.x + bb.x);
        o[1] = (short)f2bf((v.y - mu) * rr * g.y + bb.y);
        o[2] = (short)f2bf((v.z - mu) * rr * g.z + bb.z);
        o[3] = (short)f2bf((v.w - mu) * rr * g.w + bb.w);
        *(bf16x4*)(Y + (size_t)row * 256 + lane * 4) = o;
    }
}

// ---------------------------------------------------------------------------
// MFMA GEMM, 128x64 tile (BN 128->64), BK=64, global_load_lds staging.
// Smaller tile doubles blocks/CU: QKV 1.5->3 (also fixes 384-block
// imbalance), FF1 2->4 — applying R10's proven cross-block-overlap
// mechanism. Each warp owns a 64x32 sub-tile (acc[4][2]).
// EPI: 2 = bf16 gelu(+bias); 3 = qkv mode (V transposed to Vout[dim][tok]).
// ---------------------------------------------------------------------------
template <int EPI>
__global__ __launch_bounds__(256) void mfma_gemm(
    const u16* __restrict__ A, const u16* __restrict__ Bt,
    const float* __restrict__ bias, u16* __restrict__ Vout,
    void* __restrict__ Cout, int N, int K)
{
    __shared__ u16 As[128 * 64];   // 16 KB
    __shared__ u16 Bs[64 * 64];    // 8 KB
    const int tid = threadIdx.x, w = tid >> 6, lane = tid & 63;
    const int c = lane & 15, quad = lane >> 4;
    const int row0 = blockIdx.y * 128, col0 = blockIdx.x * 64;
    const int wr = w >> 1, wc = w & 1;
    const int cswz = (c & 7) << 4;

    int flvA[4], rA[4], colA[4];
#pragma unroll
    for (int ci = 0; ci < 4; ci++) {
        flvA[ci] = (w * 4 + ci) * 1024 + lane * 16;
        const int fsw = SWZ(flvA[ci]);
        rA[ci]   = fsw >> 7;
        colA[ci] = (fsw & 127) >> 1;
    }
    int flvB[2], rB[2], colB[2];
#pragma unroll
    for (int ci = 0; ci < 2; ci++) {
        flvB[ci] = (w * 2 + ci) * 1024 + lane * 16;
        const int fsw = SWZ(flvB[ci]);
        rB[ci]   = fsw >> 7;
        colB[ci] = (fsw & 127) >> 1;
    }

    f32x4 acc[4][2] = {};

    for (int k0 = 0; k0 < K; k0 += 64) {
        __syncthreads();
#pragma unroll
        for (int ci = 0; ci < 4; ci++)
            gload16(A + (size_t)(row0 + rA[ci]) * K + k0 + colA[ci],
                    (char*)As + flvA[ci]);
#pragma unroll
        for (int ci = 0; ci < 2; ci++)
            gload16(Bt + (size_t)(col0 + rB[ci]) * K + k0 + colB[ci],
                    (char*)Bs + flvB[ci]);
        __syncthreads();
#pragma unroll
        for (int kk = 0; kk < 2; kk++) {
            bf16x8 af[4], bfv[2];
#pragma unroll
            for (int i = 0; i < 4; i++)
                af[i] = *(const bf16x8*)((const char*)As +
                    ((((wr * 64 + i * 16 + c) * 64 + kk * 32 + quad * 8) * 2) ^ cswz));
#pragma unroll
            for (int j = 0; j < 2; j++)
                bfv[j] = *(const bf16x8*)((const char*)Bs +
                    ((((wc * 32 + j * 16 + c) * 64 + kk * 32 + quad * 8) * 2) ^ cswz));
#pragma unroll
            for (int i = 0; i < 4; i++)
#pragma unroll
                for (int j = 0; j < 2; j++)
                    acc[i][j] = __builtin_amdgcn_mfma_f32_16x16x32_bf16(
                        af[i], bfv[j], acc[i][j], 0, 0, 0);
        }
    }

    float bj[2];
#pragma unroll
    for (int j = 0; j < 2; j++) bj[j] = bias[col0 + wc * 32 + j * 16 + c];

    if (EPI == 3 && col0 >= 512) {
#pragma unroll
        for (int i = 0; i < 4; i++) {
            const int tok = row0 + wr * 64 + i * 16 + quad * 4;
#pragma unroll
            for (int j = 0; j < 2; j++) {
                const int dim = col0 - 512 + wc * 32 + j * 16 + c;
                bf16x4 o;
#pragma unroll
                for (int r = 0; r < 4; r++) o[r] = (short)f2bf(acc[i][j][r] + bj[j]);
                *(bf16x4*)&Vout[(size_t)dim * M_ROWS + tok] = o;
            }
        }
        return;
    }

#pragma unroll
    for (int i = 0; i < 4; i++) {
#pragma unroll
        for (int r = 0; r < 4; r++) {
            const int gr = row0 + wr * 64 + i * 16 + quad * 4 + r;
#pragma unroll
            for (int j = 0; j < 2; j++) {
                const int gc = col0 + wc * 32 + j * 16 + c;
                float v = acc[i][j][r] + bj[j];
                if (EPI == 2) v = fast_gelu(v);
                ((u16*)Cout)[(size_t)gr * N + gc] = f2bf(v);
            }
        }
    }
}

// ---------------------------------------------------------------------------
// GEMM (N=256, BM=16, BN=256) + residual + optional fused LayerNorm.
// 512 blocks = 2 independent barrier domains per CU (R10's win, unchanged).
// MERGE=1: 2-way key-split partials merged inline during A staging.
// ---------------------------------------------------------------------------
template <int DOLN, int MERGE>
__global__ __launch_bounds__(256) void gemm_ln(
    const u16* __restrict__ A, const float* __restrict__ Lmrg,
    const u16* __restrict__ Bt, const float* __restrict__ bias,
    const float* __restrict__ resid, float* __restrict__ Xout,
    const float* __restrict__ gamma, const float* __restrict__ beta,
    u16* __restrict__ Nout, int K)
{
    __shared__ u16 As[16 * 64];                 // 2 KB
    __shared__ u16 Bs[256 * 64];                // 32 KB
    __shared__ float2 red[4][16];
    const int tid = threadIdx.x, w = tid >> 6, lane = tid & 63;
    const int c = lane & 15, quad = lane >> 4;
    const int row0 = blockIdx.x * 16;
    const int cswz = (c & 7) << 4;

    // A staging: 2 KB staged by tid<128, 16B each
    const int flA  = tid * 16;                  // valid for tid<128
    const bool doA = tid < 128;
    const int fsA  = SWZ(flA);
    const int rA_m = flA >> 7, colA_m = (flA & 127) >> 1;   // MERGE reg-path
    const int rA_g = fsA >> 7, colA_g = (fsA & 127) >> 1;   // gload path

    // B staging: 32 KB, 8 x 16B per thread
    int flB[8], rB[8], colB[8];
#pragma unroll
    for (int ci = 0; ci < 8; ci++) {
        flB[ci]  = (w * 8 + ci) * 1024 + lane * 16;
        const int fsB = SWZ(flB[ci]);
        rB[ci]   = fsB >> 7;
        colB[ci] = (fsB & 127) >> 1;
    }

    f32x4 acc[4] = {};

    auto loadA = [&](int gc) -> bf16x8 {
        const int row = row0 + rA_m;
        const int head = gc >> 5;
        float ls = 0.f;
#pragma unroll
        for (int p = 0; p < KSPLIT; p++)
            ls += Lmrg[(size_t)p * M_ROWS * 8 + (size_t)row * 8 + head];
        const float inv = __builtin_amdgcn_rcpf(ls);
        float s[8] = {0.f, 0.f, 0.f, 0.f, 0.f, 0.f, 0.f, 0.f};
#pragma unroll
        for (int p = 0; p < KSPLIT; p++) {
            bf16x8 a = *(const bf16x8*)(A + (size_t)p * M_ROWS * 256
                                          + (size_t)row * 256 + gc);
#pragma unroll
            for (int j = 0; j < 8; j++) s[j] += bf2f(a[j]);
        }
        bf16x8 o;
#pragma unroll
        for (int j = 0; j < 8; j++) o[j] = (short)f2bf(s[j] * inv);
        return o;
    };

    bf16x8 pA;
    if (MERGE && doA) pA = loadA(colA_m);

    for (int k0 = 0; k0 < K; k0 += 64) {
        __syncthreads();
#pragma unroll
        for (int ci = 0; ci < 8; ci++)
            gload16(Bt + (size_t)rB[ci] * K + k0 + colB[ci], (char*)Bs + flB[ci]);
        if (MERGE) {
            if (doA) *(bf16x8*)((char*)As + fsA) = pA;
        } else {
            if (doA) gload16(A + (size_t)(row0 + rA_g) * K + k0 + colA_g,
                             (char*)As + flA);
        }
        __syncthreads();
        if (MERGE && doA && k0 + 64 < K)
            pA = loadA(k0 + 64 + colA_m);   // lands during compute
#pragma unroll
        for (int kk = 0; kk < 2; kk++) {
            bf16x8 af, bfv[4];
            af = *(const bf16x8*)((const char*)As +
                (((c * 64 + kk * 32 + quad * 8) * 2) ^ cswz));
#pragma unroll
            for (int j = 0; j < 4; j++)
                bfv[j] = *(const bf16x8*)((const char*)Bs +
                    ((((w * 64 + j * 16 + c) * 64 + kk * 32 + quad * 8) * 2) ^ cswz));
#pragma unroll
            for (int j = 0; j < 4; j++)
                acc[j] = __builtin_amdgcn_mfma_f32_16x16x32_bf16(
                    af, bfv[j], acc[j], 0, 0, 0);
        }
    }

    float bj[4];
#pragma unroll
    for (int j = 0; j < 4; j++) bj[j] = bias[w * 64 + j * 16 + c];
    float xv[4][4];
#pragma unroll
    for (int r = 0; r < 4; r++) {
        const int gr = row0 + quad * 4 + r;
#pragma unroll
        for (int j = 0; j < 4; j++) {
            const int gc = w * 64 + j * 16 + c;
            xv[j][r] = acc[j][r] + bj[j] + resid[(size_t)gr * 256 + gc];
        }
    }

    if (DOLN) {
        float sm[4], sp[4];
#pragma unroll
        for (int r = 0; r < 4; r++) {
            float s = 0.f, q = 0.f;
#pragma unroll
            for (int j = 0; j < 4; j++) { s += xv[j][r]; q += xv[j][r] * xv[j][r]; }
            sm[r] = s; sp[r] = q;
        }
#pragma unroll
        for (int off = 1; off < 16; off <<= 1)
#pragma unroll
            for (int r = 0; r < 4; r++) {
                sm[r] += __shfl_xor(sm[r], off, 64);
                sp[r] += __shfl_xor(sp[r], off, 64);
            }
        __syncthreads();
        if (c == 0) {
#pragma unroll
            for (int r = 0; r < 4; r++)
                red[w][quad * 4 + r] = make_float2(sm[r], sp[r]);
        }
        __syncthreads();
#pragma unroll
        for (int r = 0; r < 4; r++) {
            const int row = quad * 4 + r;
            float2 t0 = red[0][row], t1 = red[1][row];
            float2 t2 = red[2][row], t3 = red[3][row];
            float S = (t0.x + t1.x) + (t2.x + t3.x);
            float Q = (t0.y + t1.y) + (t2.y + t3.y);
            float mu = S * (1.0f / 256.0f);
            float var = Q * (1.0f / 256.0f) - mu * mu;
            float rr = rsqrtf(var + 1e-5f);
            const int gr = row0 + row;
#pragma unroll
            for (int j = 0; j < 4; j++) {
                const int gc = w * 64 + j * 16 + c;
                float x = xv[j][r];
                Xout[(size_t)gr * 256 + gc] = x;
                Nout[(size_t)gr * 256 + gc] =
                    f2bf((x - mu) * rr * gamma[gc] + beta[gc]);
            }
        }
    } else {
#pragma unroll
        for (int r = 0; r < 4; r++) {
            const int gr = row0 + quad * 4 + r;
#pragma unroll
            for (int j = 0; j < 4; j++)
                Xout[(size_t)gr * 256 + w * 64 + j * 16 + c] = xv[j][r];
        }
    }
}

// ---------------------------------------------------------------------------
// MFMA flash attention, key-split x2 (unchanged from R10).
// ---------------------------------------------------------------------------
__global__ __launch_bounds__(256) void attn_kernel(
    const u16* __restrict__ QKV, const u16* __restrict__ VT,
    u16* __restrict__ PO, float* __restrict__ Lp)
{
    const int h = blockIdx.y, b = blockIdx.z;
    const int part = blockIdx.x & (KSPLIT - 1);
    const int q0 = (blockIdx.x >> 1) * 128;
    const int tid = threadIdx.x, w = tid >> 6, lane = tid & 63;
    const int c = lane & 15, quad = lane >> 4;

    __shared__ u16 Kf[4096];
    __shared__ u16 Vf[4096];

    const u16* qp = QKV + (size_t)(b * T_SEQ + q0 + w * 32 + c) * QKV_N + h * 32 + quad * 8;
    bf16x8 aQ0 = *(const bf16x8*)qp;
    bf16x8 aQ1 = *(const bf16x8*)(qp + 16 * QKV_N);

    const bf16x8 bOnes = {0x3F80, 0x3F80, 0x3F80, 0x3F80,
                          0x3F80, 0x3F80, 0x3F80, 0x3F80};

    f32x4 O[2][2] = {};
    f32x4 Ol0 = {0.f, 0.f, 0.f, 0.f}, Ol1 = {0.f, 0.f, 0.f, 0.f};

    const u16* kgp = QKV + (size_t)(b * T_SEQ + w * 16 + c) * QKV_N + 256 + h * 32 + quad * 8;
    const u16* vgp = VT + ((size_t)h * 32 + (lane & 31)) * M_ROWS + b * T_SEQ
                     + (w * 2 + (lane >> 5)) * 8;
    u16* kfw = Kf + w * 512 + lane * 8;

    const int vd  = lane & 31, vdh = vd >> 4, vc = vd & 15, vhi = lane >> 5;
    const int vkh = w >> 1, vseg = w & 1;
    const int voff = ((((vkh * 2 + vdh) * 4 + 2 * vhi) * 16 + vc) * 8) + vseg * 4;

    const int kbeg = part * (T_SEQ / KSPLIT);
    const int kend = kbeg + T_SEQ / KSPLIT;

    bf16x8 gK0 = *(const bf16x8*)(kgp + (size_t)kbeg * QKV_N);
    bf16x8 gK1 = *(const bf16x8*)(kgp + (size_t)(kbeg + 64) * QKV_N);
    bf16x8 gV0 = *(const bf16x8*)(vgp + kbeg);
    bf16x8 gV1 = *(const bf16x8*)(vgp + kbeg + 64);

    for (int k0 = kbeg; k0 < kend; k0 += 128) {
        __syncthreads();
        *(bf16x8*)kfw          = gK0;
        *(bf16x8*)(kfw + 2048) = gK1;
        {
            bf16x4 l0v = __builtin_shufflevector(gV0, gV0, 0, 1, 2, 3);
            bf16x4 h0v = __builtin_shufflevector(gV0, gV0, 4, 5, 6, 7);
            bf16x4 l1v = __builtin_shufflevector(gV1, gV1, 0, 1, 2, 3);
            bf16x4 h1v = __builtin_shufflevector(gV1, gV1, 4, 5, 6, 7);
            *(bf16x4*)&Vf[voff]              = l0v;
            *(bf16x4*)&Vf[voff + 128]        = h0v;
            *(bf16x4*)&Vf[2048 + voff]       = l1v;
            *(bf16x4*)&Vf[2048 + voff + 128] = h1v;
        }
        __syncthreads();
        if (k0 + 128 < kend) {
            gK0 = *(const bf16x8*)(kgp + (size_t)(k0 + 128) * QKV_N);
            gK1 = *(const bf16x8*)(kgp + (size_t)(k0 + 192) * QKV_N);
            gV0 = *(const bf16x8*)(vgp + k0 + 128);
            gV1 = *(const bf16x8*)(vgp + k0 + 192);
        }

#pragma unroll
        for (int hf = 0; hf < 2; hf++) {
            const u16* Kb = Kf + hf * 2048;
            const u16* Vb = Vf + hf * 2048;

            unsigned pk0[4][2], pk1[4][2];
#pragma unroll
            for (int g = 0; g < 4; g++) {
                bf16x8 aK = *(const bf16x8*)&Kb[g * 512 + lane * 8];
                f32x4 S0 = __builtin_amdgcn_mfma_f32_16x16x32_bf16(
                    aK, aQ0, (f32x4){0.f, 0.f, 0.f, 0.f}, 0, 0, 0);
                f32x4 S1 = __builtin_amdgcn_mfma_f32_16x16x32_bf16(
                    aK, aQ1, (f32x4){0.f, 0.f, 0.f, 0.f}, 0, 0, 0);
                pk0[g][0] = pack2bf(__builtin_amdgcn_exp2f(S0[0]),
                                    __builtin_amdgcn_exp2f(S0[1]));
                pk0[g][1] = pack2bf(__builtin_amdgcn_exp2f(S0[2]),
                                    __builtin_amdgcn_exp2f(S0[3]));
                pk1[g][0] = pack2bf(__builtin_amdgcn_exp2f(S1[0]),
                                    __builtin_amdgcn_exp2f(S1[1]));
                pk1[g][1] = pack2bf(__builtin_amdgcn_exp2f(S1[2]),
                                    __builtin_amdgcn_exp2f(S1[3]));
            }

            __builtin_amdgcn_s_setprio(1);
#pragma unroll
            for (int kh = 0; kh < 2; kh++) {
                bf16x8 aP0 = __builtin_bit_cast(bf16x8,
                    (u32x4){pk0[2 * kh][0], pk0[2 * kh][1],
                            pk0[2 * kh + 1][0], pk0[2 * kh + 1][1]});
                bf16x8 aP1 = __builtin_bit_cast(bf16x8,
                    (u32x4){pk1[2 * kh][0], pk1[2 * kh][1],
                            pk1[2 * kh + 1][0], pk1[2 * kh + 1][1]});
                Ol0 = __builtin_amdgcn_mfma_f32_16x16x32_bf16(aP0, bOnes, Ol0, 0, 0, 0);
                Ol1 = __builtin_amdgcn_mfma_f32_16x16x32_bf16(aP1, bOnes, Ol1, 0, 0, 0);
#pragma unroll
                for (int dh = 0; dh < 2; dh++) {
                    bf16x8 bV = *(const bf16x8*)&Vb[((kh * 2 + dh) * 64 + lane) * 8];
                    O[0][dh] = __builtin_amdgcn_mfma_f32_16x16x32_bf16(aP0, bV, O[0][dh], 0, 0, 0);
                    O[1][dh] = __builtin_amdgcn_mfma_f32_16x16x32_bf16(aP1, bV, O[1][dh], 0, 0, 0);
                }
            }
            __builtin_amdgcn_s_setprio(0);
        }
    }

    u16* pb = PO + (size_t)part * M_ROWS * 256
              + (size_t)(b * T_SEQ + q0 + w * 32) * 256 + h * 32;
    if (c == 0) {
        float* lb = Lp + (size_t)part * M_ROWS * 8
                    + (size_t)(b * T_SEQ + q0 + w * 32) * 8 + h;
#pragma unroll
        for (int r = 0; r < 4; r++) {
            lb[(size_t)(quad * 4 + r) * 8]      = Ol0[r];
            lb[(size_t)(16 + quad * 4 + r) * 8] = Ol1[r];
        }
    }
#pragma unroll
    for (int r = 0; r < 4; r++) {
        int src = quad * 4 + r;
        pb[(size_t)src * 256 + c]             = f2bf(O[0][0][r]);
        pb[(size_t)src * 256 + 16 + c]        = f2bf(O[0][1][r]);
        pb[(size_t)(16 + src) * 256 + c]      = f2bf(O[1][0][r]);
        pb[(size_t)(16 + src) * 256 + 16 + c] = f2bf(O[1][1][r]);
    }
}

// ---------------------------------------------------------------------------
extern "C" void kernel_launch(void* const* d_in, const int* in_sizes, int n_in,
                              void* d_out, int out_size, void* d_ws, size_t ws_size,
                              hipStream_t stream)
{
    const float* x     = (const float*)d_in[0];
    const float* ln1_s = (const float*)d_in[1];
    const float* ln1_b = (const float*)d_in[2];
    const float* wq    = (const float*)d_in[3];
    const float* bq    = (const float*)d_in[4];
    const float* wk    = (const float*)d_in[5];
    const float* bk    = (const float*)d_in[6];
    const float* wv    = (const float*)d_in[7];
    const float* bv    = (const float*)d_in[8];
    const float* wo    = (const float*)d_in[9];
    const float* bo    = (const float*)d_in[10];
    const float* ln2_s = (const float*)d_in[11];
    const float* ln2_b = (const float*)d_in[12];
    const float* w1    = (const float*)d_in[13];
    const float* b1    = (const float*)d_in[14];
    const float* w2    = (const float*)d_in[15];
    const float* b2    = (const float*)d_in[16];

    float* X = (float*)d_out;                   // fp32 residual stream

    u16* normed = (u16*)d_ws;                               // 8192*256
    u16* qkv    = normed + (size_t)M_ROWS * 256;            // 8192*768
    u16* PO2    = qkv + (size_t)M_ROWS * QKV_N;             // 2 x 8192*256
    u16* h1     = qkv;   // spans qkv+PO2[0]: 8192*1024 (PO2[0] consumed by then)
    u16* wqkv_t = PO2 + (size_t)KSPLIT * M_ROWS * 256;      // 6*768*256
    u16* wo_t   = wqkv_t + (size_t)N_LAYERSC * QKV_N * 256; // 6*256*256
    u16* w1_t   = wo_t + (size_t)N_LAYERSC * 256 * 256;     // 6*1024*256
    u16* w2_t   = w1_t + (size_t)N_LAYERSC * D_FFC * 256;   // 6*256*1024
    float* qkvb = (float*)(w2_t + (size_t)N_LAYERSC * 256 * D_FFC); // 6*768 fp32
    u16* VTb    = (u16*)(qkvb + N_LAYERSC * QKV_N);         // 256*8192
    float* Lp   = (float*)(VTb + (size_t)256 * M_ROWS);     // 2*8192*8 fp32

    dim3 blk(256);

    // ---- ALL weight prep + X=x + ln1(layer0) in one dispatch
    prep_all<<<dim3(4626 + M_ROWS / 4), blk, 0, stream>>>(
        wq, wk, wv, wo, w1, w2, bq, bk, bv,
        wqkv_t, wo_t, w1_t, w2_t, qkvb,
        x, ln1_s, ln1_b, X, normed);

    dim3 g_qkv(QKV_N / 64, M_ROWS / 128);               // (12,64) = 768 = 3/CU
    dim3 g_ff(D_FFC / 64, M_ROWS / 128);                // (16,64) = 1024 = 4/CU
    dim3 g_ln16(M_ROWS / 16);                           // 512 blocks = 2/CU
    dim3 g_attn(KSPLIT * T_SEQ / 128, N_HEADSC, B_SZ);  // (32,8,4) = 1024 blocks

    for (int l = 0; l < N_LAYERSC; l++) {
        mfma_gemm<3><<<g_qkv, blk, 0, stream>>>(
            normed, wqkv_t + (size_t)l * QKV_N * 256, qkvb + l * QKV_N,
            VTb, qkv, QKV_N, 256);
        attn_kernel<<<g_attn, blk, 0, stream>>>(qkv, VTb, PO2, Lp);
        // Wo + resid + ln2, with the 2-way key-split merge fused into A-staging
        gemm_ln<1, 1><<<g_ln16, blk, 0, stream>>>(
            PO2, Lp, wo_t + (size_t)l * 256 * 256, bo + l * 256, X,
            X, ln2_s + l * 256, ln2_b + l * 256, VTb, 256);
        mfma_gemm<2><<<g_ff, blk, 0, stream>>>(
            VTb, w1_t + (size_t)l * D_FFC * 256, b1 + l * D_FFC,
            nullptr, h1, D_FFC, 256);
        if (l + 1 < N_LAYERSC) {
            gemm_ln<1, 0><<<g_ln16, blk, 0, stream>>>(
                h1, nullptr, w2_t + (size_t)l * 256 * D_FFC,
                b2 + l * 256, X, X, ln1_s + (l + 1) * 256,
                ln1_b + (l + 1) * 256, normed, D_FFC);
        } else {
            gemm_ln<0, 0><<<g_ln16, blk, 0, stream>>>(
                h1, nullptr, w2_t + (size_t)l * 256 * D_FFC,
                b2 + l * 256, X, X, nullptr, nullptr, nullptr, D_FFC);
        }
    }
}